// Round 14
// baseline (1293.141 us; speedup 1.0000x reference)
//
#include <hip/hip_runtime.h>

#define NND 100000
#define NE  1600000
#define NF  512
#define NH  64
#define NC  40

#define BROWS 256                          // rows per bucket
#define NB ((NND + BROWS - 1) / BROWS)     // 391 buckets
#define BCAP 4864                          // bucket capacity (mean 4096 + 12 sigma)
#define EPB 8192                           // edges per scatter block (8/thread)
#define NEB ((NE + EPB - 1) / EPB)         // 196 blocks
#define W10PAD 52                          // bf16 LDS pad for W10
#define HPAD1 68                           // f32 LDS pad for spmm1 hacc (16B-aligned rows)
#define HPAD2 41                           // f32 LDS pad for spmm2 hacc

typedef unsigned short u16;
typedef unsigned int   u32;
typedef __attribute__((ext_vector_type(8))) __bf16 bf16x8;
typedef __attribute__((ext_vector_type(8))) u16    u16x8;
typedef __attribute__((ext_vector_type(4))) float  f32x4;

__device__ __forceinline__ u16 f2bf(float f) {          // f32 -> bf16 RNE
  u32 u = __builtin_bit_cast(u32, f);
  u += 0x7FFFu + ((u >> 16) & 1u);
  return (u16)(u >> 16);
}
__device__ __forceinline__ u32 pack2(float a, float b) {
  return (u32)f2bf(a) | ((u32)f2bf(b) << 16);
}
__device__ __forceinline__ float bf2f(u16 h) {
  return __builtin_bit_cast(float, (u32)h << 16);
}
__device__ __forceinline__ bf16x8 pack8(const float4& a, const float4& b) {
  uint4 v;
  v.x = pack2(a.x, a.y); v.y = pack2(a.z, a.w);
  v.z = pack2(b.x, b.y); v.w = pack2(b.z, b.w);
  return __builtin_bit_cast(bf16x8, v);
}

// ---------------- W1 [512,64] f32 -> W1T [64,512] bf16 ; block 0 zeroes gcursor ----------------
__global__ __launch_bounds__(256) void w1t_k(const float* __restrict__ W1,
                                             u16* __restrict__ w1t,
                                             int* __restrict__ gcursor) {
  if (blockIdx.x == 0) {
    for (int i = threadIdx.x; i < NB; i += 256) gcursor[i] = 0;
  }
  int i = blockIdx.x * 256 + threadIdx.x;
  if (i >= NF * NH) return;
  int n = i >> 9, k = i & 511;
  w1t[i] = f2bf(W1[(size_t)k * NH + n]);
}

// ---------------- GEMM1 (bf16 MFMA): s1[N,64] = bf16(x[N,512] @ W1) ----------------
__global__ __launch_bounds__(256) void gemm1_k(const float* __restrict__ x,
                                               const u16* __restrict__ w1t,
                                               u16* __restrict__ out) {
  __shared__ u16 Bs[2][64][72];
  const int t = threadIdx.x, w = t >> 6, lane = t & 63;
  const int l15 = lane & 15, l4 = lane >> 4;
  const int rowBase = blockIdx.x * 128;
  const int r0 = rowBase + w * 32 + l15;
  const float* pa0 = x + (size_t)min(r0, NND - 1) * NF + l4 * 8;
  const float* pa1 = x + (size_t)min(r0 + 16, NND - 1) * NF + l4 * 8;

  f32x4 acc[2][4];
#pragma unroll
  for (int i = 0; i < 2; ++i)
#pragma unroll
    for (int j = 0; j < 4; ++j) acc[i][j] = (f32x4){0.f, 0.f, 0.f, 0.f};

  uint4  bR[2];
  float4 aR[2][2][2];   // [a0/a1][s][half]

  auto issueB = [&](int k0) {
#pragma unroll
    for (int i = 0; i < 2; ++i) {
      int c = t + i * 256;
      bR[i] = *(const uint4*)(w1t + (size_t)(c >> 3) * NF + k0 + (c & 7) * 8);
    }
  };
  auto issueA = [&](int k0) {
#pragma unroll
    for (int s = 0; s < 2; ++s) {
      const float* q0 = pa0 + k0 + s * 32;
      const float* q1 = pa1 + k0 + s * 32;
      aR[0][s][0] = *(const float4*)(q0);
      aR[0][s][1] = *(const float4*)(q0 + 4);
      aR[1][s][0] = *(const float4*)(q1);
      aR[1][s][1] = *(const float4*)(q1 + 4);
    }
  };

  issueB(0);
  issueA(0);
  for (int it = 0; it < 8; ++it) {
    const int b = it & 1;
#pragma unroll
    for (int i = 0; i < 2; ++i) {          // stage B tile
      int c = t + i * 256;
      *(uint4*)&Bs[b][c >> 3][(c & 7) * 8] = bR[i];
    }
    bf16x8 fa0[2], fa1[2];
#pragma unroll
    for (int s = 0; s < 2; ++s) {
      fa0[s] = pack8(aR[0][s][0], aR[0][s][1]);
      fa1[s] = pack8(aR[1][s][0], aR[1][s][1]);
    }
    if (it < 7) { issueB((it + 1) * 64); issueA((it + 1) * 64); }
    __syncthreads();
#pragma unroll
    for (int s = 0; s < 2; ++s) {
#pragma unroll
      for (int ct = 0; ct < 4; ++ct) {
        bf16x8 bb = *(const bf16x8*)&Bs[b][ct * 16 + l15][s * 32 + l4 * 8];
        acc[0][ct] = __builtin_amdgcn_mfma_f32_16x16x32_bf16(fa0[s], bb, acc[0][ct], 0, 0, 0);
        acc[1][ct] = __builtin_amdgcn_mfma_f32_16x16x32_bf16(fa1[s], bb, acc[1][ct], 0, 0, 0);
      }
    }
  }

#pragma unroll
  for (int rt = 0; rt < 2; ++rt)
#pragma unroll
    for (int ct = 0; ct < 4; ++ct)
#pragma unroll
      for (int i = 0; i < 4; ++i) {
        int row = rowBase + w * 32 + rt * 16 + l4 * 4 + i;   // C/D: col=lane&15, row=(lane>>4)*4+reg
        if (row < NND) out[(size_t)row * NH + ct * 16 + l15] = f2bf(acc[rt][ct][i]);
      }
}

// ---------------- bucket scatter (fixed-capacity buckets, bump-allocated) ----------------
// eb1 entry: (col<<8 | row&255, val); bucket b owns eb1[b*BCAP .. b*BCAP+count)
__global__ __launch_bounds__(1024) void bscatter_k(const float* __restrict__ vals,
                                                   const int* __restrict__ rows,
                                                   const int* __restrict__ cols,
                                                   int* __restrict__ gcursor,
                                                   int2* __restrict__ eb1) {
  __shared__ int cnt[NB];
  __shared__ int base[NB];
  const int t = threadIdx.x;
  for (int i = t; i < NB; i += 1024) cnt[i] = 0;
  __syncthreads();
  const int gb = blockIdx.x * EPB;
  int bin[8], rnk[8], rr[8], cc[8];
  float vv[8];
#pragma unroll
  for (int k = 0; k < 8; ++k) {
    int i = gb + t + k * 1024;
    if (i < NE) {
      rr[k] = rows[i]; cc[k] = cols[i]; vv[k] = vals[i];
      bin[k] = rr[k] >> 8;
      rnk[k] = atomicAdd(&cnt[bin[k]], 1);
    } else bin[k] = -1;
  }
  __syncthreads();
  for (int i = t; i < NB; i += 1024)
    if (cnt[i]) base[i] = i * BCAP + atomicAdd(&gcursor[i], cnt[i]);
  __syncthreads();
#pragma unroll
  for (int k = 0; k < 8; ++k) {
    if (bin[k] >= 0) {
      int pos = base[bin[k]] + rnk[k];
      eb1[pos] = make_int2((int)(((u32)cc[k] << 8) | (u32)(rr[k] & 255)),
                           __float_as_int(vv[k]));
    }
  }
}

// ---------------- SpMM1 atomic: ds_add accumulate + fused GEMM2 ----------------
// One block per bucket, 16 waves. Unsorted edges -> native LDS f32 atomics into
// hacc[256][68]; then bias+relu+bf16 A-frags straight from LDS -> MFMA with W10.
__global__ __launch_bounds__(1024) void spmm1a_k(const int* __restrict__ gcursor,
                                                 const int2* __restrict__ eb1,
                                                 const u16* __restrict__ s1,
                                                 const float* __restrict__ b1,
                                                 const float* __restrict__ W10,
                                                 u16* __restrict__ s2) {
  __shared__ float hacc[BROWS][HPAD1];   // 69.6 KB
  __shared__ u16 w10s[64 * W10PAD];      // 6.7 KB
  __shared__ float b1s[64];
  const int bkt = blockIdx.x, t = threadIdx.x;
  const int w = t >> 6, lane = t & 63;
  const int nE = min(gcursor[bkt], BCAP);
  const int beg = bkt * BCAP;
  for (int i = t; i < 64 * W10PAD; i += 1024) {
    int k = i / W10PAD, c = i - k * W10PAD;
    w10s[i] = (c < NC) ? f2bf(W10[k * NC + c]) : (u16)0;
  }
  if (t < 64) b1s[t] = b1[t];
  for (int i = t; i < BROWS * HPAD1; i += 1024) ((float*)hacc)[i] = 0.f;
  __syncthreads();

  for (int j0 = w * 64; j0 < nE; j0 += 1024) {
    int2 e = eb1[beg + min(j0 + lane, nE - 1)];
    int n = min(64, nE - j0);
    int j = 0;
    for (; j + 3 < n; j += 4) {
      u32 m0 = (u32)__shfl(e.x, j, 64);     float v0 = __shfl(__int_as_float(e.y), j, 64);
      u32 m1 = (u32)__shfl(e.x, j + 1, 64); float v1 = __shfl(__int_as_float(e.y), j + 1, 64);
      u32 m2 = (u32)__shfl(e.x, j + 2, 64); float v2 = __shfl(__int_as_float(e.y), j + 2, 64);
      u32 m3 = (u32)__shfl(e.x, j + 3, 64); float v3 = __shfl(__int_as_float(e.y), j + 3, 64);
      float f0 = bf2f(s1[(size_t)(m0 >> 8) * NH + lane]);
      float f1 = bf2f(s1[(size_t)(m1 >> 8) * NH + lane]);
      float f2 = bf2f(s1[(size_t)(m2 >> 8) * NH + lane]);
      float f3 = bf2f(s1[(size_t)(m3 >> 8) * NH + lane]);
      unsafeAtomicAdd(&hacc[m0 & 255u][lane], v0 * f0);
      unsafeAtomicAdd(&hacc[m1 & 255u][lane], v1 * f1);
      unsafeAtomicAdd(&hacc[m2 & 255u][lane], v2 * f2);
      unsafeAtomicAdd(&hacc[m3 & 255u][lane], v3 * f3);
    }
    for (; j < n; ++j) {
      u32 m0 = (u32)__shfl(e.x, j, 64);
      float v0 = __shfl(__int_as_float(e.y), j, 64);
      unsafeAtomicAdd(&hacc[m0 & 255u][lane],
                      v0 * bf2f(s1[(size_t)(m0 >> 8) * NH + lane]));
    }
  }
  __syncthreads();

  // epilogue: A-frag = bf16(relu(hacc + b1)), rows w*16+l15, k = l4*8(+32)
  const int l15 = lane & 15, l4 = lane >> 4;
  bf16x8 afr[2];
#pragma unroll
  for (int s = 0; s < 2; ++s) {
    u16x8 aw;
#pragma unroll
    for (int j = 0; j < 8; ++j) {
      int k = s * 32 + l4 * 8 + j;
      aw[j] = f2bf(fmaxf(hacc[w * 16 + l15][k] + b1s[k], 0.f));
    }
    afr[s] = __builtin_bit_cast(bf16x8, aw);
  }

  f32x4 acc[3];
#pragma unroll
  for (int ct = 0; ct < 3; ++ct) acc[ct] = (f32x4){0.f, 0.f, 0.f, 0.f};
#pragma unroll
  for (int ct = 0; ct < 3; ++ct) {
#pragma unroll
    for (int kk = 0; kk < 2; ++kk) {
      u16x8 bw;
#pragma unroll
      for (int j = 0; j < 8; ++j)
        bw[j] = w10s[(kk * 32 + l4 * 8 + j) * W10PAD + ct * 16 + l15];
      acc[ct] = __builtin_amdgcn_mfma_f32_16x16x32_bf16(
          afr[kk], __builtin_bit_cast(bf16x8, bw), acc[ct], 0, 0, 0);
    }
  }
  // C/D: col=lane&15, row=(lane>>4)*4+reg
#pragma unroll
  for (int ct = 0; ct < 3; ++ct) {
    int c = ct * 16 + l15;
#pragma unroll
    for (int i = 0; i < 4; ++i) {
      int grow = bkt * BROWS + w * 16 + l4 * 4 + i;
      if (c < NC && grow < NND) s2[(size_t)grow * NC + c] = f2bf(acc[ct][i]);
    }
  }
}

// ---------------- SpMM2 atomic: ds_add accumulate + b10 + log_softmax ----------------
__global__ __launch_bounds__(1024) void spmm2a_k(const int* __restrict__ gcursor,
                                                 const int2* __restrict__ eb1,
                                                 const u16* __restrict__ s2,
                                                 const float* __restrict__ b10,
                                                 float* __restrict__ out) {
  __shared__ float hacc[BROWS][HPAD2];   // 42 KB
  const int bkt = blockIdx.x, t = threadIdx.x;
  const int w = t >> 6, lane = t & 63;
  const int nE = min(gcursor[bkt], BCAP);
  const int beg = bkt * BCAP;
  for (int i = t; i < BROWS * HPAD2; i += 1024) ((float*)hacc)[i] = 0.f;
  __syncthreads();

  const int off0 = (lane < NC) ? lane : 0;
  const bool act = lane < NC;
  for (int j0 = w * 64; j0 < nE; j0 += 1024) {
    int2 e = eb1[beg + min(j0 + lane, nE - 1)];
    int n = min(64, nE - j0);
    int j = 0;
    for (; j + 3 < n; j += 4) {
      u32 m0 = (u32)__shfl(e.x, j, 64);     float v0 = __shfl(__int_as_float(e.y), j, 64);
      u32 m1 = (u32)__shfl(e.x, j + 1, 64); float v1 = __shfl(__int_as_float(e.y), j + 1, 64);
      u32 m2 = (u32)__shfl(e.x, j + 2, 64); float v2 = __shfl(__int_as_float(e.y), j + 2, 64);
      u32 m3 = (u32)__shfl(e.x, j + 3, 64); float v3 = __shfl(__int_as_float(e.y), j + 3, 64);
      if (act) {
        float f0 = bf2f(s2[(size_t)(m0 >> 8) * NC + off0]);
        float f1 = bf2f(s2[(size_t)(m1 >> 8) * NC + off0]);
        float f2 = bf2f(s2[(size_t)(m2 >> 8) * NC + off0]);
        float f3 = bf2f(s2[(size_t)(m3 >> 8) * NC + off0]);
        unsafeAtomicAdd(&hacc[m0 & 255u][off0], v0 * f0);
        unsafeAtomicAdd(&hacc[m1 & 255u][off0], v1 * f1);
        unsafeAtomicAdd(&hacc[m2 & 255u][off0], v2 * f2);
        unsafeAtomicAdd(&hacc[m3 & 255u][off0], v3 * f3);
      }
    }
    for (; j < n; ++j) {
      u32 m0 = (u32)__shfl(e.x, j, 64);
      float v0 = __shfl(__int_as_float(e.y), j, 64);
      if (act)
        unsafeAtomicAdd(&hacc[m0 & 255u][off0],
                        v0 * bf2f(s2[(size_t)(m0 >> 8) * NC + off0]));
    }
  }
  __syncthreads();

  const float bias = act ? b10[lane] : 0.f;
#pragma unroll 1
  for (int i = 0; i < 16; ++i) {
    int r8 = w * 16 + i;
    int grow = bkt * BROWS + r8;
    if (grow >= NND) continue;
    float vv = act ? hacc[r8][lane] + bias : -INFINITY;
    float m = vv;
#pragma unroll
    for (int o = 32; o; o >>= 1) m = fmaxf(m, __shfl_xor(m, o, 64));
    float e = act ? __expf(vv - m) : 0.f;
    float ss = e;
#pragma unroll
    for (int o = 32; o; o >>= 1) ss += __shfl_xor(ss, o, 64);
    if (act) out[(size_t)grow * NC + lane] = vv - m - __logf(ss);
  }
}

extern "C" void kernel_launch(void* const* d_in, const int* in_sizes, int n_in,
                              void* d_out, int out_size, void* d_ws, size_t ws_size,
                              hipStream_t stream) {
  const float* x    = (const float*)d_in[0];
  const float* adj  = (const float*)d_in[1];
  const float* W1   = (const float*)d_in[2];
  const float* b1   = (const float*)d_in[3];
  const float* W10  = (const float*)d_in[4];
  const float* b10  = (const float*)d_in[5];
  const int*   erow = (const int*)d_in[6];
  const int*   ecol = (const int*)d_in[7];
  float* out = (float*)d_out;

  char* p = (char*)d_ws;
  u16*  s1  = (u16*)p;    p += (size_t)NND * NH * 2;        // 12.8 MB
  u16*  s2  = (u16*)p;    p += (size_t)NND * NC * 2;        // 8 MB
  u16*  w1t = (u16*)p;    p += (size_t)NF * NH * 2;         // 64 KB
  int2* eb1 = (int2*)p;   p += (size_t)NB * BCAP * 8;       // 15.2 MB
  int* gcursor = (int*)p;

  w1t_k<<<(NF * NH + 255) / 256, 256, 0, stream>>>(W1, w1t, gcursor);
  bscatter_k<<<NEB, 1024, 0, stream>>>(adj, erow, ecol, gcursor, eb1);

  gemm1_k<<<(NND + 127) / 128, 256, 0, stream>>>(x, w1t, s1);
  spmm1a_k<<<NB, 1024, 0, stream>>>(gcursor, eb1, s1, b1, W10, s2);
  spmm2a_k<<<NB, 1024, 0, stream>>>(gcursor, eb1, s2, b10, out);
}

// Round 15
// 180.687 us; speedup vs baseline: 7.1568x; 7.1568x over previous
//
#include <hip/hip_runtime.h>

#define NND 100000
#define NE  1600000
#define NF  512
#define NH  64
#define NC  40

#define BROWS 256                          // rows per bucket
#define NB ((NND + BROWS - 1) / BROWS)     // 391 buckets
#define BCAP 4864                          // bucket capacity (mean 4096 + 12 sigma)
#define EPB 8192                           // edges per scatter block (8/thread)
#define NEB ((NE + EPB - 1) / EPB)         // 196 blocks
#define W10PAD 52                          // bf16 LDS pad for W10
#define HPAD 68                            // bf16 LDS pad for h block

typedef unsigned short u16;
typedef unsigned int   u32;
typedef __attribute__((ext_vector_type(8))) __bf16 bf16x8;
typedef __attribute__((ext_vector_type(8))) u16    u16x8;
typedef __attribute__((ext_vector_type(4))) float  f32x4;

__device__ __forceinline__ u16 f2bf(float f) {          // f32 -> bf16 RNE
  u32 u = __builtin_bit_cast(u32, f);
  u += 0x7FFFu + ((u >> 16) & 1u);
  return (u16)(u >> 16);
}
__device__ __forceinline__ u32 pack2(float a, float b) {
  return (u32)f2bf(a) | ((u32)f2bf(b) << 16);
}
__device__ __forceinline__ float bf2f(u16 h) {
  return __builtin_bit_cast(float, (u32)h << 16);
}
__device__ __forceinline__ bf16x8 pack8(const float4& a, const float4& b) {
  uint4 v;
  v.x = pack2(a.x, a.y); v.y = pack2(a.z, a.w);
  v.z = pack2(b.x, b.y); v.w = pack2(b.z, b.w);
  return __builtin_bit_cast(bf16x8, v);
}

// ---------------- W1 [512,64] f32 -> W1T [64,512] bf16 ; block 0 zeroes gcursor ----------------
__global__ __launch_bounds__(256) void w1t_k(const float* __restrict__ W1,
                                             u16* __restrict__ w1t,
                                             int* __restrict__ gcursor) {
  if (blockIdx.x == 0) {
    for (int i = threadIdx.x; i < NB; i += 256) gcursor[i] = 0;
  }
  int i = blockIdx.x * 256 + threadIdx.x;
  if (i >= NF * NH) return;
  int n = i >> 9, k = i & 511;
  w1t[i] = f2bf(W1[(size_t)k * NH + n]);
}

// ---------------- GEMM1 (bf16 MFMA): s1[N,64] = bf16(x[N,512] @ W1) ----------------
__global__ __launch_bounds__(256) void gemm1_k(const float* __restrict__ x,
                                               const u16* __restrict__ w1t,
                                               u16* __restrict__ out) {
  __shared__ u16 Bs[2][64][72];
  const int t = threadIdx.x, w = t >> 6, lane = t & 63;
  const int l15 = lane & 15, l4 = lane >> 4;
  const int rowBase = blockIdx.x * 128;
  const int r0 = rowBase + w * 32 + l15;
  const float* pa0 = x + (size_t)min(r0, NND - 1) * NF + l4 * 8;
  const float* pa1 = x + (size_t)min(r0 + 16, NND - 1) * NF + l4 * 8;

  f32x4 acc[2][4];
#pragma unroll
  for (int i = 0; i < 2; ++i)
#pragma unroll
    for (int j = 0; j < 4; ++j) acc[i][j] = (f32x4){0.f, 0.f, 0.f, 0.f};

  uint4  bR[2];
  float4 aR[2][2][2];   // [a0/a1][s][half]

  auto issueB = [&](int k0) {
#pragma unroll
    for (int i = 0; i < 2; ++i) {
      int c = t + i * 256;
      bR[i] = *(const uint4*)(w1t + (size_t)(c >> 3) * NF + k0 + (c & 7) * 8);
    }
  };
  auto issueA = [&](int k0) {
#pragma unroll
    for (int s = 0; s < 2; ++s) {
      const float* q0 = pa0 + k0 + s * 32;
      const float* q1 = pa1 + k0 + s * 32;
      aR[0][s][0] = *(const float4*)(q0);
      aR[0][s][1] = *(const float4*)(q0 + 4);
      aR[1][s][0] = *(const float4*)(q1);
      aR[1][s][1] = *(const float4*)(q1 + 4);
    }
  };

  issueB(0);
  issueA(0);
  for (int it = 0; it < 8; ++it) {
    const int b = it & 1;
#pragma unroll
    for (int i = 0; i < 2; ++i) {          // stage B tile
      int c = t + i * 256;
      *(uint4*)&Bs[b][c >> 3][(c & 7) * 8] = bR[i];
    }
    bf16x8 fa0[2], fa1[2];
#pragma unroll
    for (int s = 0; s < 2; ++s) {
      fa0[s] = pack8(aR[0][s][0], aR[0][s][1]);
      fa1[s] = pack8(aR[1][s][0], aR[1][s][1]);
    }
    if (it < 7) { issueB((it + 1) * 64); issueA((it + 1) * 64); }
    __syncthreads();
#pragma unroll
    for (int s = 0; s < 2; ++s) {
#pragma unroll
      for (int ct = 0; ct < 4; ++ct) {
        bf16x8 bb = *(const bf16x8*)&Bs[b][ct * 16 + l15][s * 32 + l4 * 8];
        acc[0][ct] = __builtin_amdgcn_mfma_f32_16x16x32_bf16(fa0[s], bb, acc[0][ct], 0, 0, 0);
        acc[1][ct] = __builtin_amdgcn_mfma_f32_16x16x32_bf16(fa1[s], bb, acc[1][ct], 0, 0, 0);
      }
    }
  }

#pragma unroll
  for (int rt = 0; rt < 2; ++rt)
#pragma unroll
    for (int ct = 0; ct < 4; ++ct)
#pragma unroll
      for (int i = 0; i < 4; ++i) {
        int row = rowBase + w * 32 + rt * 16 + l4 * 4 + i;   // C/D: col=lane&15, row=(lane>>4)*4+reg
        if (row < NND) out[(size_t)row * NH + ct * 16 + l15] = f2bf(acc[rt][ct][i]);
      }
}

// ---------------- bucket scatter (fixed-capacity buckets, bump-allocated) ----------------
// eb1 entry: (col<<8 | row&255, val); bucket b owns eb1[b*BCAP .. b*BCAP+count)
__global__ __launch_bounds__(1024) void bscatter_k(const float* __restrict__ vals,
                                                   const int* __restrict__ rows,
                                                   const int* __restrict__ cols,
                                                   int* __restrict__ gcursor,
                                                   int2* __restrict__ eb1) {
  __shared__ int cnt[NB];
  __shared__ int base[NB];
  const int t = threadIdx.x;
  for (int i = t; i < NB; i += 1024) cnt[i] = 0;
  __syncthreads();
  const int gb = blockIdx.x * EPB;
  int bin[8], rnk[8], rr[8], cc[8];
  float vv[8];
#pragma unroll
  for (int k = 0; k < 8; ++k) {
    int i = gb + t + k * 1024;
    if (i < NE) {
      rr[k] = rows[i]; cc[k] = cols[i]; vv[k] = vals[i];
      bin[k] = rr[k] >> 8;
      rnk[k] = atomicAdd(&cnt[bin[k]], 1);
    } else bin[k] = -1;
  }
  __syncthreads();
  for (int i = t; i < NB; i += 1024)
    if (cnt[i]) base[i] = i * BCAP + atomicAdd(&gcursor[i], cnt[i]);
  __syncthreads();
#pragma unroll
  for (int k = 0; k < 8; ++k) {
    if (bin[k] >= 0) {
      int pos = base[bin[k]] + rnk[k];
      eb1[pos] = make_int2((int)(((u32)cc[k] << 8) | (u32)(rr[k] & 255)),
                           __float_as_int(vv[k]));
    }
  }
}

// ---------------- SpMM1 fused sort+gather+GEMM2; exports sorted edges + rowoff/rowcnt ----------------
// Gather uses half-wave edge pairs: lanes 0-31 even edges, 32-63 odd edges,
// dword (2-feature) loads, zero shfl in the inner loop.
__global__ __launch_bounds__(1024) void spmm1f_k(const int* __restrict__ gcursor,
                                                 const int2* __restrict__ eb1,
                                                 const u16* __restrict__ s1,
                                                 const float* __restrict__ b1,
                                                 const float* __restrict__ W10,
                                                 u16* __restrict__ s2,
                                                 int2* __restrict__ eb2,
                                                 int* __restrict__ rowoff,
                                                 int* __restrict__ rowcnt) {
  __shared__ int2 se[BCAP];            // 38.9 KB; reused as per-wave h blocks after gather
  __shared__ u16 w10s[64 * W10PAD];    // 6.7 KB bf16 W10 [k][c]
  __shared__ int cnt[BROWS];
  __shared__ int sc[BROWS];
  __shared__ int wsum[4];
  const int bkt = blockIdx.x, t = threadIdx.x;
  const int w = t >> 6, lane = t & 63;
  const int half = lane >> 5, fl = lane & 31;   // feature pair index (features 2fl, 2fl+1)
  const int nE = min(gcursor[bkt], BCAP);
  const int beg = bkt * BCAP;
  for (int i = t; i < 64 * W10PAD; i += 1024) {
    int k = i / W10PAD, c = i - k * W10PAD;
    w10s[i] = (c < NC) ? f2bf(W10[k * NC + c]) : (u16)0;
  }
  if (t < BROWS) cnt[t] = 0;
  __syncthreads();
  int2 mye[5]; int myrow[5], myrank[5];
#pragma unroll
  for (int k = 0; k < 5; ++k) {
    int i = t + k * 1024;
    myrow[k] = -1;
    if (i < nE) {
      int2 e = eb1[beg + i];
      mye[k] = e;
      myrow[k] = e.x & 255;
      myrank[k] = atomicAdd(&cnt[myrow[k]], 1);
    }
  }
  __syncthreads();
  int c0 = 0, inc = 0;
  if (t < BROWS) {
    c0 = cnt[t]; inc = c0;
#pragma unroll
    for (int off = 1; off < 64; off <<= 1) {
      int u = __shfl_up(inc, off, 64);
      if ((t & 63) >= off) inc += u;
    }
    if ((t & 63) == 63) wsum[t >> 6] = inc;
  }
  __syncthreads();
  if (t < BROWS) {
    int pre = 0;
#pragma unroll
    for (int k = 0; k < 4; ++k) pre += (k < (t >> 6)) ? wsum[k] : 0;
    int ex = pre + inc - c0;
    sc[t] = ex;
    rowoff[bkt * BROWS + t] = beg + ex;      // absolute eb2 offset for spmm2
    rowcnt[bkt * BROWS + t] = c0;            // per-row count for spmm2
  }
  __syncthreads();
#pragma unroll
  for (int k = 0; k < 5; ++k)
    if (myrow[k] >= 0)
      se[sc[myrow[k]] + myrank[k]] = make_int2((int)((u32)mye[k].x >> 8), mye[k].y);
  __syncthreads();

  // export sorted edges (coalesced) so spmm2 skips the sort
#pragma unroll
  for (int k = 0; k < 5; ++k) {
    int i = t + k * 1024;
    if (i < nE) eb2[beg + i] = se[i];
  }

  // gather: wave w owns rows w*16..w*16+15; half-wave edge pairs, dword loads
  const float2 bias2 = *(const float2*)(b1 + fl * 2);
  u32 hpack[16];
#pragma unroll 1
  for (int i = 0; i < 16; ++i) {
    int r8 = w * 16 + i;
    int s = sc[r8], n = cnt[r8];
    float a0 = 0.f, a1 = 0.f, a2 = 0.f, a3 = 0.f;
    int j = 0;
    for (; j + 3 < n; j += 4) {          // two pairs (4 edges)
      int2 e0 = se[s + j + half];
      int2 e1 = se[s + j + 2 + half];
      float v0 = __int_as_float(e0.y);
      float v1 = __int_as_float(e1.y);
      u32 f0 = *(const u32*)(s1 + (size_t)e0.x * NH + fl * 2);
      u32 f1 = *(const u32*)(s1 + (size_t)e1.x * NH + fl * 2);
      a0 = fmaf(v0, bf2f((u16)f0), a0);
      a1 = fmaf(v0, bf2f((u16)(f0 >> 16)), a1);
      a2 = fmaf(v1, bf2f((u16)f1), a2);
      a3 = fmaf(v1, bf2f((u16)(f1 >> 16)), a3);
    }
    for (; j < n; j += 2) {              // tail (1-3 edges)
      int idx = j + half;
      bool ok = idx < n;
      int2 e = se[s + (ok ? idx : 0)];
      float v = ok ? __int_as_float(e.y) : 0.f;
      u32 f = *(const u32*)(s1 + (size_t)e.x * NH + fl * 2);
      a0 = fmaf(v, bf2f((u16)f), a0);
      a1 = fmaf(v, bf2f((u16)(f >> 16)), a1);
    }
    float t0 = a0 + a2, t1 = a1 + a3;
    t0 += __shfl_xor(t0, 32, 64);        // combine even/odd halves
    t1 += __shfl_xor(t1, 32, 64);
    hpack[i] = pack2(fmaxf(t0 + bias2.x, 0.f), fmaxf(t1 + bias2.y, 0.f));
  }
  __syncthreads();   // all waves done reading se -> safe to reuse as h blocks

  u16* hl = (u16*)se + (size_t)w * 16 * HPAD;
  if (half == 0) {
#pragma unroll
    for (int i = 0; i < 16; ++i) *(u32*)&hl[i * HPAD + fl * 2] = hpack[i];
  }

  const int l15 = lane & 15, l4 = lane >> 4;
  bf16x8 afr[2];
  afr[0] = *(const bf16x8*)&hl[l15 * HPAD + l4 * 8];
  afr[1] = *(const bf16x8*)&hl[l15 * HPAD + 32 + l4 * 8];

  f32x4 acc[3];
#pragma unroll
  for (int ct = 0; ct < 3; ++ct) acc[ct] = (f32x4){0.f, 0.f, 0.f, 0.f};
#pragma unroll
  for (int ct = 0; ct < 3; ++ct) {
#pragma unroll
    for (int kk = 0; kk < 2; ++kk) {
      u16x8 bw;
#pragma unroll
      for (int j = 0; j < 8; ++j)
        bw[j] = w10s[(kk * 32 + l4 * 8 + j) * W10PAD + ct * 16 + l15];
      acc[ct] = __builtin_amdgcn_mfma_f32_16x16x32_bf16(
          afr[kk], __builtin_bit_cast(bf16x8, bw), acc[ct], 0, 0, 0);
    }
  }
#pragma unroll
  for (int ct = 0; ct < 3; ++ct) {
    int c = ct * 16 + l15;
#pragma unroll
    for (int i = 0; i < 4; ++i) {
      int grow = bkt * BROWS + w * 16 + l4 * 4 + i;
      if (c < NC && grow < NND) s2[(size_t)grow * NC + c] = f2bf(acc[ct][i]);
    }
  }
}

// ---------------- SpMM2 half-bucket: pre-sorted edges + b10 + log_softmax ----------------
// 782 blocks x 512 threads; block (bkt, half) handles 128 rows. No sort, no scan.
__global__ __launch_bounds__(512) void spmm2h_k(const int2* __restrict__ eb2,
                                                const int* __restrict__ rowoff,
                                                const int* __restrict__ rowcnt,
                                                const u16* __restrict__ s2,
                                                const float* __restrict__ b10,
                                                float* __restrict__ out) {
  __shared__ int2 se[BCAP];
  __shared__ int roff[128];
  __shared__ int rcnt[128];
  const int bh = blockIdx.x;
  const int bkt = bh >> 1, half = bh & 1;
  const int t = threadIdx.x, w = t >> 6, lane = t & 63;
  const int rowBase = bkt * BROWS + half * 128;
  if (t < 128) {
    roff[t] = rowoff[rowBase + t];
    rcnt[t] = rowcnt[rowBase + t];
  }
  __syncthreads();
  const int base = roff[0];
  const int nE = min(roff[127] + rcnt[127] - base, BCAP);
  for (int i = t; i < nE; i += 512) se[i] = eb2[base + i];
  __syncthreads();

  const int off0 = (lane < NC) ? lane : 0;
  const float bias = (lane < NC) ? b10[lane] : 0.f;
#pragma unroll 1
  for (int i = 0; i < 16; ++i) {
    int r8 = w * 16 + i;                     // 8 waves x 16 rows = 128
    int s = roff[r8] - base, n = rcnt[r8];
    float a0 = 0.f, a1 = 0.f, a2 = 0.f, a3 = 0.f;
    int j = 0;
    for (; j + 3 < n; j += 4) {
      int2 e0 = se[s + j], e1 = se[s + j + 1], e2 = se[s + j + 2], e3 = se[s + j + 3];
      a0 = fmaf(__int_as_float(e0.y), bf2f(s2[(size_t)e0.x * NC + off0]), a0);
      a1 = fmaf(__int_as_float(e1.y), bf2f(s2[(size_t)e1.x * NC + off0]), a1);
      a2 = fmaf(__int_as_float(e2.y), bf2f(s2[(size_t)e2.x * NC + off0]), a2);
      a3 = fmaf(__int_as_float(e3.y), bf2f(s2[(size_t)e3.x * NC + off0]), a3);
    }
    for (; j < n; ++j) {
      int2 e0 = se[s + j];
      a0 = fmaf(__int_as_float(e0.y), bf2f(s2[(size_t)e0.x * NC + off0]), a0);
    }
    int grow = rowBase + r8;
    if (grow >= NND) continue;
    float vv = (lane < NC) ? (a0 + a1) + (a2 + a3) + bias : -INFINITY;
    float m = vv;
#pragma unroll
    for (int o = 32; o; o >>= 1) m = fmaxf(m, __shfl_xor(m, o, 64));
    float e = (lane < NC) ? __expf(vv - m) : 0.f;
    float ss = e;
#pragma unroll
    for (int o = 32; o; o >>= 1) ss += __shfl_xor(ss, o, 64);
    if (lane < NC) out[(size_t)grow * NC + lane] = vv - m - __logf(ss);
  }
}

extern "C" void kernel_launch(void* const* d_in, const int* in_sizes, int n_in,
                              void* d_out, int out_size, void* d_ws, size_t ws_size,
                              hipStream_t stream) {
  const float* x    = (const float*)d_in[0];
  const float* adj  = (const float*)d_in[1];
  const float* W1   = (const float*)d_in[2];
  const float* b1   = (const float*)d_in[3];
  const float* W10  = (const float*)d_in[4];
  const float* b10  = (const float*)d_in[5];
  const int*   erow = (const int*)d_in[6];
  const int*   ecol = (const int*)d_in[7];
  float* out = (float*)d_out;

  char* p = (char*)d_ws;
  u16*  s1  = (u16*)p;    p += (size_t)NND * NH * 2;        // 12.8 MB
  u16*  s2  = (u16*)p;    p += (size_t)NND * NC * 2;        // 8 MB
  u16*  w1t = (u16*)p;    p += (size_t)NF * NH * 2;         // 64 KB
  int2* eb1 = (int2*)p;   p += (size_t)NB * BCAP * 8;       // 15.2 MB
  int2* eb2 = (int2*)p;   p += (size_t)NB * BCAP * 8;       // 15.2 MB
  int* rowoff = (int*)p;  p += (size_t)NB * BROWS * 4;      // 400 KB
  int* rowcnt = (int*)p;  p += (size_t)NB * BROWS * 4;      // 400 KB
  int* gcursor = (int*)p;

  w1t_k<<<(NF * NH + 255) / 256, 256, 0, stream>>>(W1, w1t, gcursor);
  bscatter_k<<<NEB, 1024, 0, stream>>>(adj, erow, ecol, gcursor, eb1);

  gemm1_k<<<(NND + 127) / 128, 256, 0, stream>>>(x, w1t, s1);
  spmm1f_k<<<NB, 1024, 0, stream>>>(gcursor, eb1, s1, b1, W10, s2, eb2, rowoff, rowcnt);
  spmm2h_k<<<NB * 2, 512, 0, stream>>>(eb2, rowoff, rowcnt, s2, b10, out);
}

// Round 16
// 171.173 us; speedup vs baseline: 7.5546x; 1.0556x over previous
//
#include <hip/hip_runtime.h>

#define NND 100000
#define NE  1600000
#define NF  512
#define NH  64
#define NC  40

#define BROWS 256                          // rows per bucket
#define NB ((NND + BROWS - 1) / BROWS)     // 391 buckets
#define BCAP 4864                          // bucket capacity (mean 4096 + 12 sigma)
#define EPB 8192                           // edges per scatter block (8/thread)
#define NEB ((NE + EPB - 1) / EPB)         // 196 blocks
#define W10PAD 52                          // bf16 LDS pad for W10
#define HPAD 68                            // bf16 LDS pad for h block

typedef unsigned short u16;
typedef unsigned int   u32;
typedef __attribute__((ext_vector_type(8))) __bf16 bf16x8;
typedef __attribute__((ext_vector_type(8))) u16    u16x8;
typedef __attribute__((ext_vector_type(4))) float  f32x4;

__device__ __forceinline__ u16 f2bf(float f) {          // f32 -> bf16 RNE
  u32 u = __builtin_bit_cast(u32, f);
  u += 0x7FFFu + ((u >> 16) & 1u);
  return (u16)(u >> 16);
}
__device__ __forceinline__ u32 pack2(float a, float b) {
  return (u32)f2bf(a) | ((u32)f2bf(b) << 16);
}
__device__ __forceinline__ float bf2f(u16 h) {
  return __builtin_bit_cast(float, (u32)h << 16);
}
__device__ __forceinline__ bf16x8 pack8(const float4& a, const float4& b) {
  uint4 v;
  v.x = pack2(a.x, a.y); v.y = pack2(a.z, a.w);
  v.z = pack2(b.x, b.y); v.w = pack2(b.z, b.w);
  return __builtin_bit_cast(bf16x8, v);
}

// ---------------- W1 [512,64] f32 -> W1T [64,512] bf16 ; block 0 zeroes gcursor ----------------
__global__ __launch_bounds__(256) void w1t_k(const float* __restrict__ W1,
                                             u16* __restrict__ w1t,
                                             int* __restrict__ gcursor) {
  if (blockIdx.x == 0) {
    for (int i = threadIdx.x; i < NB; i += 256) gcursor[i] = 0;
  }
  int i = blockIdx.x * 256 + threadIdx.x;
  if (i >= NF * NH) return;
  int n = i >> 9, k = i & 511;
  w1t[i] = f2bf(W1[(size_t)k * NH + n]);
}

// ---------------- GEMM1 (bf16 MFMA): s1[N,64] = bf16(x[N,512] @ W1) ----------------
__global__ __launch_bounds__(256) void gemm1_k(const float* __restrict__ x,
                                               const u16* __restrict__ w1t,
                                               u16* __restrict__ out) {
  __shared__ u16 Bs[2][64][72];
  const int t = threadIdx.x, w = t >> 6, lane = t & 63;
  const int l15 = lane & 15, l4 = lane >> 4;
  const int rowBase = blockIdx.x * 128;
  const int r0 = rowBase + w * 32 + l15;
  const float* pa0 = x + (size_t)min(r0, NND - 1) * NF + l4 * 8;
  const float* pa1 = x + (size_t)min(r0 + 16, NND - 1) * NF + l4 * 8;

  f32x4 acc[2][4];
#pragma unroll
  for (int i = 0; i < 2; ++i)
#pragma unroll
    for (int j = 0; j < 4; ++j) acc[i][j] = (f32x4){0.f, 0.f, 0.f, 0.f};

  uint4  bR[2];
  float4 aR[2][2][2];   // [a0/a1][s][half]

  auto issueB = [&](int k0) {
#pragma unroll
    for (int i = 0; i < 2; ++i) {
      int c = t + i * 256;
      bR[i] = *(const uint4*)(w1t + (size_t)(c >> 3) * NF + k0 + (c & 7) * 8);
    }
  };
  auto issueA = [&](int k0) {
#pragma unroll
    for (int s = 0; s < 2; ++s) {
      const float* q0 = pa0 + k0 + s * 32;
      const float* q1 = pa1 + k0 + s * 32;
      aR[0][s][0] = *(const float4*)(q0);
      aR[0][s][1] = *(const float4*)(q0 + 4);
      aR[1][s][0] = *(const float4*)(q1);
      aR[1][s][1] = *(const float4*)(q1 + 4);
    }
  };

  issueB(0);
  issueA(0);
  for (int it = 0; it < 8; ++it) {
    const int b = it & 1;
#pragma unroll
    for (int i = 0; i < 2; ++i) {          // stage B tile
      int c = t + i * 256;
      *(uint4*)&Bs[b][c >> 3][(c & 7) * 8] = bR[i];
    }
    bf16x8 fa0[2], fa1[2];
#pragma unroll
    for (int s = 0; s < 2; ++s) {
      fa0[s] = pack8(aR[0][s][0], aR[0][s][1]);
      fa1[s] = pack8(aR[1][s][0], aR[1][s][1]);
    }
    if (it < 7) { issueB((it + 1) * 64); issueA((it + 1) * 64); }
    __syncthreads();
#pragma unroll
    for (int s = 0; s < 2; ++s) {
#pragma unroll
      for (int ct = 0; ct < 4; ++ct) {
        bf16x8 bb = *(const bf16x8*)&Bs[b][ct * 16 + l15][s * 32 + l4 * 8];
        acc[0][ct] = __builtin_amdgcn_mfma_f32_16x16x32_bf16(fa0[s], bb, acc[0][ct], 0, 0, 0);
        acc[1][ct] = __builtin_amdgcn_mfma_f32_16x16x32_bf16(fa1[s], bb, acc[1][ct], 0, 0, 0);
      }
    }
  }

#pragma unroll
  for (int rt = 0; rt < 2; ++rt)
#pragma unroll
    for (int ct = 0; ct < 4; ++ct)
#pragma unroll
      for (int i = 0; i < 4; ++i) {
        int row = rowBase + w * 32 + rt * 16 + l4 * 4 + i;   // C/D: col=lane&15, row=(lane>>4)*4+reg
        if (row < NND) out[(size_t)row * NH + ct * 16 + l15] = f2bf(acc[rt][ct][i]);
      }
}

// ---------------- bucket scatter (fixed-capacity buckets, bump-allocated) ----------------
// eb1 entry: (col<<8 | row&255, val); bucket b owns eb1[b*BCAP .. b*BCAP+count)
__global__ __launch_bounds__(1024) void bscatter_k(const float* __restrict__ vals,
                                                   const int* __restrict__ rows,
                                                   const int* __restrict__ cols,
                                                   int* __restrict__ gcursor,
                                                   int2* __restrict__ eb1) {
  __shared__ int cnt[NB];
  __shared__ int base[NB];
  const int t = threadIdx.x;
  for (int i = t; i < NB; i += 1024) cnt[i] = 0;
  __syncthreads();
  const int gb = blockIdx.x * EPB;
  int bin[8], rnk[8], rr[8], cc[8];
  float vv[8];
#pragma unroll
  for (int k = 0; k < 8; ++k) {
    int i = gb + t + k * 1024;
    if (i < NE) {
      rr[k] = rows[i]; cc[k] = cols[i]; vv[k] = vals[i];
      bin[k] = rr[k] >> 8;
      rnk[k] = atomicAdd(&cnt[bin[k]], 1);
    } else bin[k] = -1;
  }
  __syncthreads();
  for (int i = t; i < NB; i += 1024)
    if (cnt[i]) base[i] = i * BCAP + atomicAdd(&gcursor[i], cnt[i]);
  __syncthreads();
#pragma unroll
  for (int k = 0; k < 8; ++k) {
    if (bin[k] >= 0) {
      int pos = base[bin[k]] + rnk[k];
      eb1[pos] = make_int2((int)(((u32)cc[k] << 8) | (u32)(rr[k] & 255)),
                           __float_as_int(vv[k]));
    }
  }
}

// ---------------- SpMM1 fused sort+gather+GEMM2; exports sorted edges + rowoff/rowcnt ----------------
// Gather uses half-wave edge pairs: lanes 0-31 even edges, 32-63 odd edges,
// dword (2-feature) loads, zero shfl in the inner loop.
__global__ __launch_bounds__(1024) void spmm1f_k(const int* __restrict__ gcursor,
                                                 const int2* __restrict__ eb1,
                                                 const u16* __restrict__ s1,
                                                 const float* __restrict__ b1,
                                                 const float* __restrict__ W10,
                                                 u16* __restrict__ s2,
                                                 int2* __restrict__ eb2,
                                                 int* __restrict__ rowoff,
                                                 int* __restrict__ rowcnt) {
  __shared__ int2 se[BCAP];            // 38.9 KB; reused as per-wave h blocks after gather
  __shared__ u16 w10s[64 * W10PAD];    // 6.7 KB bf16 W10 [k][c]
  __shared__ int cnt[BROWS];
  __shared__ int sc[BROWS];
  __shared__ int wsum[4];
  const int bkt = blockIdx.x, t = threadIdx.x;
  const int w = t >> 6, lane = t & 63;
  const int half = lane >> 5, fl = lane & 31;   // feature pair index (features 2fl, 2fl+1)
  const int nE = min(gcursor[bkt], BCAP);
  const int beg = bkt * BCAP;
  for (int i = t; i < 64 * W10PAD; i += 1024) {
    int k = i / W10PAD, c = i - k * W10PAD;
    w10s[i] = (c < NC) ? f2bf(W10[k * NC + c]) : (u16)0;
  }
  if (t < BROWS) cnt[t] = 0;
  __syncthreads();
  int2 mye[5]; int myrow[5], myrank[5];
#pragma unroll
  for (int k = 0; k < 5; ++k) {
    int i = t + k * 1024;
    myrow[k] = -1;
    if (i < nE) {
      int2 e = eb1[beg + i];
      mye[k] = e;
      myrow[k] = e.x & 255;
      myrank[k] = atomicAdd(&cnt[myrow[k]], 1);
    }
  }
  __syncthreads();
  int c0 = 0, inc = 0;
  if (t < BROWS) {
    c0 = cnt[t]; inc = c0;
#pragma unroll
    for (int off = 1; off < 64; off <<= 1) {
      int u = __shfl_up(inc, off, 64);
      if ((t & 63) >= off) inc += u;
    }
    if ((t & 63) == 63) wsum[t >> 6] = inc;
  }
  __syncthreads();
  if (t < BROWS) {
    int pre = 0;
#pragma unroll
    for (int k = 0; k < 4; ++k) pre += (k < (t >> 6)) ? wsum[k] : 0;
    int ex = pre + inc - c0;
    sc[t] = ex;
    rowoff[bkt * BROWS + t] = beg + ex;      // absolute eb2 offset for spmm2
    rowcnt[bkt * BROWS + t] = c0;            // per-row count for spmm2
  }
  __syncthreads();
#pragma unroll
  for (int k = 0; k < 5; ++k)
    if (myrow[k] >= 0)
      se[sc[myrow[k]] + myrank[k]] = make_int2((int)((u32)mye[k].x >> 8), mye[k].y);
  __syncthreads();

  // export sorted edges (coalesced) so spmm2 skips the sort
#pragma unroll
  for (int k = 0; k < 5; ++k) {
    int i = t + k * 1024;
    if (i < nE) eb2[beg + i] = se[i];
  }

  // gather: wave w owns rows w*16..w*16+15; half-wave edge pairs, dword loads
  const float2 bias2 = *(const float2*)(b1 + fl * 2);
  u32 hpack[16];
#pragma unroll 1
  for (int i = 0; i < 16; ++i) {
    int r8 = w * 16 + i;
    int s = sc[r8], n = cnt[r8];
    float a0 = 0.f, a1 = 0.f, a2 = 0.f, a3 = 0.f;
    int j = 0;
    for (; j + 3 < n; j += 4) {          // two pairs (4 edges)
      int2 e0 = se[s + j + half];
      int2 e1 = se[s + j + 2 + half];
      float v0 = __int_as_float(e0.y);
      float v1 = __int_as_float(e1.y);
      u32 f0 = *(const u32*)(s1 + (size_t)e0.x * NH + fl * 2);
      u32 f1 = *(const u32*)(s1 + (size_t)e1.x * NH + fl * 2);
      a0 = fmaf(v0, bf2f((u16)f0), a0);
      a1 = fmaf(v0, bf2f((u16)(f0 >> 16)), a1);
      a2 = fmaf(v1, bf2f((u16)f1), a2);
      a3 = fmaf(v1, bf2f((u16)(f1 >> 16)), a3);
    }
    for (; j < n; j += 2) {              // tail (1-3 edges)
      int idx = j + half;
      bool ok = idx < n;
      int2 e = se[s + (ok ? idx : 0)];
      float v = ok ? __int_as_float(e.y) : 0.f;
      u32 f = *(const u32*)(s1 + (size_t)e.x * NH + fl * 2);
      a0 = fmaf(v, bf2f((u16)f), a0);
      a1 = fmaf(v, bf2f((u16)(f >> 16)), a1);
    }
    float t0 = a0 + a2, t1 = a1 + a3;
    t0 += __shfl_xor(t0, 32, 64);        // combine even/odd halves
    t1 += __shfl_xor(t1, 32, 64);
    hpack[i] = pack2(fmaxf(t0 + bias2.x, 0.f), fmaxf(t1 + bias2.y, 0.f));
  }
  __syncthreads();   // all waves done reading se -> safe to reuse as h blocks

  u16* hl = (u16*)se + (size_t)w * 16 * HPAD;
  if (half == 0) {
#pragma unroll
    for (int i = 0; i < 16; ++i) *(u32*)&hl[i * HPAD + fl * 2] = hpack[i];
  }

  const int l15 = lane & 15, l4 = lane >> 4;
  bf16x8 afr[2];
  afr[0] = *(const bf16x8*)&hl[l15 * HPAD + l4 * 8];
  afr[1] = *(const bf16x8*)&hl[l15 * HPAD + 32 + l4 * 8];

  f32x4 acc[3];
#pragma unroll
  for (int ct = 0; ct < 3; ++ct) acc[ct] = (f32x4){0.f, 0.f, 0.f, 0.f};
#pragma unroll
  for (int ct = 0; ct < 3; ++ct) {
#pragma unroll
    for (int kk = 0; kk < 2; ++kk) {
      u16x8 bw;
#pragma unroll
      for (int j = 0; j < 8; ++j)
        bw[j] = w10s[(kk * 32 + l4 * 8 + j) * W10PAD + ct * 16 + l15];
      acc[ct] = __builtin_amdgcn_mfma_f32_16x16x32_bf16(
          afr[kk], __builtin_bit_cast(bf16x8, bw), acc[ct], 0, 0, 0);
    }
  }
#pragma unroll
  for (int ct = 0; ct < 3; ++ct) {
    int c = ct * 16 + l15;
#pragma unroll
    for (int i = 0; i < 4; ++i) {
      int grow = bkt * BROWS + w * 16 + l4 * 4 + i;
      if (c < NC && grow < NND) s2[(size_t)grow * NC + c] = f2bf(acc[ct][i]);
    }
  }
}

// ---------------- SpMM2 half-bucket: half-wave edge pairs + b10 + log_softmax ----------------
// 782 blocks x 512 threads; block (bkt, half) handles 128 rows. No sort, no scan.
// Lanes 0-31 even edges, 32-63 odd; fl=lane&31 owns class pair (2fl, 2fl+1), fl<20 active.
__global__ __launch_bounds__(512) void spmm2h_k(const int2* __restrict__ eb2,
                                                const int* __restrict__ rowoff,
                                                const int* __restrict__ rowcnt,
                                                const u16* __restrict__ s2,
                                                const float* __restrict__ b10,
                                                float* __restrict__ out) {
  __shared__ int2 se[BCAP];
  __shared__ int roff[128];
  __shared__ int rcnt[128];
  const int bh = blockIdx.x;
  const int bkt = bh >> 1, bhalf = bh & 1;
  const int t = threadIdx.x, w = t >> 6, lane = t & 63;
  const int half = lane >> 5, fl = lane & 31;
  const bool act = fl < (NC / 2);            // fl < 20
  const int fo = act ? fl * 2 : 0;           // in-bounds class-pair offset
  const int rowBase = bkt * BROWS + bhalf * 128;
  if (t < 128) {
    roff[t] = rowoff[rowBase + t];
    rcnt[t] = rowcnt[rowBase + t];
  }
  __syncthreads();
  const int base = roff[0];
  const int nE = min(roff[127] + rcnt[127] - base, BCAP);
  for (int i = t; i < nE; i += 512) se[i] = eb2[base + i];
  __syncthreads();

  const float2 bias2 = act ? *(const float2*)(b10 + fo) : make_float2(0.f, 0.f);
#pragma unroll 1
  for (int i = 0; i < 16; ++i) {
    int r8 = w * 16 + i;                     // 8 waves x 16 rows = 128
    int s = roff[r8] - base, n = rcnt[r8];
    float a0 = 0.f, a1 = 0.f, a2 = 0.f, a3 = 0.f;
    int j = 0;
    for (; j + 3 < n; j += 4) {              // two pairs (4 edges)
      int2 e0 = se[s + j + half];
      int2 e1 = se[s + j + 2 + half];
      float v0 = __int_as_float(e0.y);
      float v1 = __int_as_float(e1.y);
      u32 f0 = *(const u32*)(s2 + (size_t)e0.x * NC + fo);
      u32 f1 = *(const u32*)(s2 + (size_t)e1.x * NC + fo);
      a0 = fmaf(v0, bf2f((u16)f0), a0);
      a1 = fmaf(v0, bf2f((u16)(f0 >> 16)), a1);
      a2 = fmaf(v1, bf2f((u16)f1), a2);
      a3 = fmaf(v1, bf2f((u16)(f1 >> 16)), a3);
    }
    for (; j < n; j += 2) {                  // tail (1-3 edges)
      int idx = j + half;
      bool ok = idx < n;
      int2 e = se[s + (ok ? idx : 0)];
      float v = ok ? __int_as_float(e.y) : 0.f;
      u32 f = *(const u32*)(s2 + (size_t)e.x * NC + fo);
      a0 = fmaf(v, bf2f((u16)f), a0);
      a1 = fmaf(v, bf2f((u16)(f >> 16)), a1);
    }
    float t0 = a0 + a2, t1 = a1 + a3;
    t0 += __shfl_xor(t0, 32, 64);            // combine even/odd halves
    t1 += __shfl_xor(t1, 32, 64);
    int grow = rowBase + r8;
    if (grow >= NND) continue;
    float v0 = act ? t0 + bias2.x : -INFINITY;
    float v1 = act ? t1 + bias2.y : -INFINITY;
    float m = fmaxf(v0, v1);
#pragma unroll
    for (int o = 16; o; o >>= 1) m = fmaxf(m, __shfl_xor(m, o, 64));  // within 32-group
    float e0 = act ? __expf(v0 - m) : 0.f;
    float e1 = act ? __expf(v1 - m) : 0.f;
    float ss = e0 + e1;
#pragma unroll
    for (int o = 16; o; o >>= 1) ss += __shfl_xor(ss, o, 64);
    float l = __logf(ss);
    if (act && half == 0)
      *(float2*)(out + (size_t)grow * NC + fo) = make_float2(v0 - m - l, v1 - m - l);
  }
}

extern "C" void kernel_launch(void* const* d_in, const int* in_sizes, int n_in,
                              void* d_out, int out_size, void* d_ws, size_t ws_size,
                              hipStream_t stream) {
  const float* x    = (const float*)d_in[0];
  const float* adj  = (const float*)d_in[1];
  const float* W1   = (const float*)d_in[2];
  const float* b1   = (const float*)d_in[3];
  const float* W10  = (const float*)d_in[4];
  const float* b10  = (const float*)d_in[5];
  const int*   erow = (const int*)d_in[6];
  const int*   ecol = (const int*)d_in[7];
  float* out = (float*)d_out;

  char* p = (char*)d_ws;
  u16*  s1  = (u16*)p;    p += (size_t)NND * NH * 2;        // 12.8 MB
  u16*  s2  = (u16*)p;    p += (size_t)NND * NC * 2;        // 8 MB
  u16*  w1t = (u16*)p;    p += (size_t)NF * NH * 2;         // 64 KB
  int2* eb1 = (int2*)p;   p += (size_t)NB * BCAP * 8;       // 15.2 MB
  int2* eb2 = (int2*)p;   p += (size_t)NB * BCAP * 8;       // 15.2 MB
  int* rowoff = (int*)p;  p += (size_t)NB * BROWS * 4;      // 400 KB
  int* rowcnt = (int*)p;  p += (size_t)NB * BROWS * 4;      // 400 KB
  int* gcursor = (int*)p;

  w1t_k<<<(NF * NH + 255) / 256, 256, 0, stream>>>(W1, w1t, gcursor);
  bscatter_k<<<NEB, 1024, 0, stream>>>(adj, erow, ecol, gcursor, eb1);

  gemm1_k<<<(NND + 127) / 128, 256, 0, stream>>>(x, w1t, s1);
  spmm1f_k<<<NB, 1024, 0, stream>>>(gcursor, eb1, s1, b1, W10, s2, eb2, rowoff, rowcnt);
  spmm2h_k<<<NB * 2, 512, 0, stream>>>(eb2, rowoff, rowcnt, s2, b10, out);
}

// Round 17
// 165.781 us; speedup vs baseline: 7.8003x; 1.0325x over previous
//
#include <hip/hip_runtime.h>

#define NND 100000
#define NE  1600000
#define NF  512
#define NH  64
#define NC  40

#define BROWS 256                          // rows per bucket
#define NB ((NND + BROWS - 1) / BROWS)     // 391 buckets
#define BCAP 4864                          // bucket capacity (mean 4096 + 12 sigma)
#define EPB 8192                           // edges per scatter block (8/thread)
#define NEB ((NE + EPB - 1) / EPB)         // 196 blocks
#define W10PAD 52                          // bf16 LDS pad for W10
#define HPAD 68                            // bf16 LDS pad for h block

typedef unsigned short u16;
typedef unsigned int   u32;
typedef __attribute__((ext_vector_type(8))) __bf16 bf16x8;
typedef __attribute__((ext_vector_type(8))) u16    u16x8;
typedef __attribute__((ext_vector_type(4))) float  f32x4;

__device__ __forceinline__ u16 f2bf(float f) {          // f32 -> bf16 RNE
  u32 u = __builtin_bit_cast(u32, f);
  u += 0x7FFFu + ((u >> 16) & 1u);
  return (u16)(u >> 16);
}
__device__ __forceinline__ u32 pack2(float a, float b) {
  return (u32)f2bf(a) | ((u32)f2bf(b) << 16);
}
__device__ __forceinline__ float bf2f(u16 h) {
  return __builtin_bit_cast(float, (u32)h << 16);
}
__device__ __forceinline__ bf16x8 pack8(const float4& a, const float4& b) {
  uint4 v;
  v.x = pack2(a.x, a.y); v.y = pack2(a.z, a.w);
  v.z = pack2(b.x, b.y); v.w = pack2(b.z, b.w);
  return __builtin_bit_cast(bf16x8, v);
}

// ---------------- W1 [512,64] f32 -> W1T [64,512] bf16 ; block 0 zeroes gcursor ----------------
__global__ __launch_bounds__(256) void w1t_k(const float* __restrict__ W1,
                                             u16* __restrict__ w1t,
                                             int* __restrict__ gcursor) {
  if (blockIdx.x == 0) {
    for (int i = threadIdx.x; i < NB; i += 256) gcursor[i] = 0;
  }
  int i = blockIdx.x * 256 + threadIdx.x;
  if (i >= NF * NH) return;
  int n = i >> 9, k = i & 511;
  w1t[i] = f2bf(W1[(size_t)k * NH + n]);
}

// ---------------- GEMM1 (bf16 MFMA): s1[N,64] = bf16(x[N,512] @ W1) ----------------
__global__ __launch_bounds__(256) void gemm1_k(const float* __restrict__ x,
                                               const u16* __restrict__ w1t,
                                               u16* __restrict__ out) {
  __shared__ u16 Bs[2][64][72];
  const int t = threadIdx.x, w = t >> 6, lane = t & 63;
  const int l15 = lane & 15, l4 = lane >> 4;
  const int rowBase = blockIdx.x * 128;
  const int r0 = rowBase + w * 32 + l15;
  const float* pa0 = x + (size_t)min(r0, NND - 1) * NF + l4 * 8;
  const float* pa1 = x + (size_t)min(r0 + 16, NND - 1) * NF + l4 * 8;

  f32x4 acc[2][4];
#pragma unroll
  for (int i = 0; i < 2; ++i)
#pragma unroll
    for (int j = 0; j < 4; ++j) acc[i][j] = (f32x4){0.f, 0.f, 0.f, 0.f};

  uint4  bR[2];
  float4 aR[2][2][2];   // [a0/a1][s][half]

  auto issueB = [&](int k0) {
#pragma unroll
    for (int i = 0; i < 2; ++i) {
      int c = t + i * 256;
      bR[i] = *(const uint4*)(w1t + (size_t)(c >> 3) * NF + k0 + (c & 7) * 8);
    }
  };
  auto issueA = [&](int k0) {
#pragma unroll
    for (int s = 0; s < 2; ++s) {
      const float* q0 = pa0 + k0 + s * 32;
      const float* q1 = pa1 + k0 + s * 32;
      aR[0][s][0] = *(const float4*)(q0);
      aR[0][s][1] = *(const float4*)(q0 + 4);
      aR[1][s][0] = *(const float4*)(q1);
      aR[1][s][1] = *(const float4*)(q1 + 4);
    }
  };

  issueB(0);
  issueA(0);
  for (int it = 0; it < 8; ++it) {
    const int b = it & 1;
#pragma unroll
    for (int i = 0; i < 2; ++i) {          // stage B tile
      int c = t + i * 256;
      *(uint4*)&Bs[b][c >> 3][(c & 7) * 8] = bR[i];
    }
    bf16x8 fa0[2], fa1[2];
#pragma unroll
    for (int s = 0; s < 2; ++s) {
      fa0[s] = pack8(aR[0][s][0], aR[0][s][1]);
      fa1[s] = pack8(aR[1][s][0], aR[1][s][1]);
    }
    if (it < 7) { issueB((it + 1) * 64); issueA((it + 1) * 64); }
    __syncthreads();
#pragma unroll
    for (int s = 0; s < 2; ++s) {
#pragma unroll
      for (int ct = 0; ct < 4; ++ct) {
        bf16x8 bb = *(const bf16x8*)&Bs[b][ct * 16 + l15][s * 32 + l4 * 8];
        acc[0][ct] = __builtin_amdgcn_mfma_f32_16x16x32_bf16(fa0[s], bb, acc[0][ct], 0, 0, 0);
        acc[1][ct] = __builtin_amdgcn_mfma_f32_16x16x32_bf16(fa1[s], bb, acc[1][ct], 0, 0, 0);
      }
    }
  }

#pragma unroll
  for (int rt = 0; rt < 2; ++rt)
#pragma unroll
    for (int ct = 0; ct < 4; ++ct)
#pragma unroll
      for (int i = 0; i < 4; ++i) {
        int row = rowBase + w * 32 + rt * 16 + l4 * 4 + i;   // C/D: col=lane&15, row=(lane>>4)*4+reg
        if (row < NND) out[(size_t)row * NH + ct * 16 + l15] = f2bf(acc[rt][ct][i]);
      }
}

// ---------------- bucket scatter (fixed-capacity buckets, bump-allocated) ----------------
// eb1 entry: (col<<8 | row&255, val); bucket b owns eb1[b*BCAP .. b*BCAP+count)
__global__ __launch_bounds__(1024) void bscatter_k(const float* __restrict__ vals,
                                                   const int* __restrict__ rows,
                                                   const int* __restrict__ cols,
                                                   int* __restrict__ gcursor,
                                                   int2* __restrict__ eb1) {
  __shared__ int cnt[NB];
  __shared__ int base[NB];
  const int t = threadIdx.x;
  for (int i = t; i < NB; i += 1024) cnt[i] = 0;
  __syncthreads();
  const int gb = blockIdx.x * EPB;
  int bin[8], rnk[8], rr[8], cc[8];
  float vv[8];
#pragma unroll
  for (int k = 0; k < 8; ++k) {
    int i = gb + t + k * 1024;
    if (i < NE) {
      rr[k] = rows[i]; cc[k] = cols[i]; vv[k] = vals[i];
      bin[k] = rr[k] >> 8;
      rnk[k] = atomicAdd(&cnt[bin[k]], 1);
    } else bin[k] = -1;
  }
  __syncthreads();
  for (int i = t; i < NB; i += 1024)
    if (cnt[i]) base[i] = i * BCAP + atomicAdd(&gcursor[i], cnt[i]);
  __syncthreads();
#pragma unroll
  for (int k = 0; k < 8; ++k) {
    if (bin[k] >= 0) {
      int pos = base[bin[k]] + rnk[k];
      eb1[pos] = make_int2((int)(((u32)cc[k] << 8) | (u32)(rr[k] & 255)),
                           __float_as_int(vv[k]));
    }
  }
}

// ---------------- SpMM1 fused sort+gather+GEMM2; exports sorted edges + rowoff/rowcnt ----------------
// Gather: half-wave edge pairs, 4 pairs (8 edges) per iteration for MLP depth 4.
__global__ __launch_bounds__(1024) void spmm1f_k(const int* __restrict__ gcursor,
                                                 const int2* __restrict__ eb1,
                                                 const u16* __restrict__ s1,
                                                 const float* __restrict__ b1,
                                                 const float* __restrict__ W10,
                                                 u16* __restrict__ s2,
                                                 int2* __restrict__ eb2,
                                                 int* __restrict__ rowoff,
                                                 int* __restrict__ rowcnt) {
  __shared__ int2 se[BCAP];            // 38.9 KB; reused as per-wave h blocks after gather
  __shared__ u16 w10s[64 * W10PAD];    // 6.7 KB bf16 W10 [k][c]
  __shared__ int cnt[BROWS];
  __shared__ int sc[BROWS];
  __shared__ int wsum[4];
  const int bkt = blockIdx.x, t = threadIdx.x;
  const int w = t >> 6, lane = t & 63;
  const int half = lane >> 5, fl = lane & 31;   // feature pair index (features 2fl, 2fl+1)
  const int nE = min(gcursor[bkt], BCAP);
  const int beg = bkt * BCAP;
  for (int i = t; i < 64 * W10PAD; i += 1024) {
    int k = i / W10PAD, c = i - k * W10PAD;
    w10s[i] = (c < NC) ? f2bf(W10[k * NC + c]) : (u16)0;
  }
  if (t < BROWS) cnt[t] = 0;
  __syncthreads();
  int2 mye[5]; int myrow[5], myrank[5];
#pragma unroll
  for (int k = 0; k < 5; ++k) {
    int i = t + k * 1024;
    myrow[k] = -1;
    if (i < nE) {
      int2 e = eb1[beg + i];
      mye[k] = e;
      myrow[k] = e.x & 255;
      myrank[k] = atomicAdd(&cnt[myrow[k]], 1);
    }
  }
  __syncthreads();
  int c0 = 0, inc = 0;
  if (t < BROWS) {
    c0 = cnt[t]; inc = c0;
#pragma unroll
    for (int off = 1; off < 64; off <<= 1) {
      int u = __shfl_up(inc, off, 64);
      if ((t & 63) >= off) inc += u;
    }
    if ((t & 63) == 63) wsum[t >> 6] = inc;
  }
  __syncthreads();
  if (t < BROWS) {
    int pre = 0;
#pragma unroll
    for (int k = 0; k < 4; ++k) pre += (k < (t >> 6)) ? wsum[k] : 0;
    int ex = pre + inc - c0;
    sc[t] = ex;
    rowoff[bkt * BROWS + t] = beg + ex;      // absolute eb2 offset for spmm2
    rowcnt[bkt * BROWS + t] = c0;            // per-row count for spmm2
  }
  __syncthreads();
#pragma unroll
  for (int k = 0; k < 5; ++k)
    if (myrow[k] >= 0)
      se[sc[myrow[k]] + myrank[k]] = make_int2((int)((u32)mye[k].x >> 8), mye[k].y);
  __syncthreads();

  // export sorted edges (coalesced) so spmm2 skips the sort
#pragma unroll
  for (int k = 0; k < 5; ++k) {
    int i = t + k * 1024;
    if (i < nE) eb2[beg + i] = se[i];
  }

  // gather: wave w owns rows w*16..w*16+15; half-wave pairs, 8-edge unroll
  const float2 bias2 = *(const float2*)(b1 + fl * 2);
  u32 hpack[16];
#pragma unroll 1
  for (int i = 0; i < 16; ++i) {
    int r8 = w * 16 + i;
    int s = sc[r8], n = cnt[r8];
    float a0 = 0.f, a1 = 0.f, a2 = 0.f, a3 = 0.f;
    float a4 = 0.f, a5 = 0.f, a6 = 0.f, a7 = 0.f;
    int j = 0;
    for (; j + 7 < n; j += 8) {          // four pairs (8 edges), MLP depth 4
      int2 e0 = se[s + j + half];
      int2 e1 = se[s + j + 2 + half];
      int2 e2 = se[s + j + 4 + half];
      int2 e3 = se[s + j + 6 + half];
      u32 f0 = *(const u32*)(s1 + (size_t)e0.x * NH + fl * 2);
      u32 f1 = *(const u32*)(s1 + (size_t)e1.x * NH + fl * 2);
      u32 f2 = *(const u32*)(s1 + (size_t)e2.x * NH + fl * 2);
      u32 f3 = *(const u32*)(s1 + (size_t)e3.x * NH + fl * 2);
      float v0 = __int_as_float(e0.y), v1 = __int_as_float(e1.y);
      float v2 = __int_as_float(e2.y), v3 = __int_as_float(e3.y);
      a0 = fmaf(v0, bf2f((u16)f0), a0);
      a1 = fmaf(v0, bf2f((u16)(f0 >> 16)), a1);
      a2 = fmaf(v1, bf2f((u16)f1), a2);
      a3 = fmaf(v1, bf2f((u16)(f1 >> 16)), a3);
      a4 = fmaf(v2, bf2f((u16)f2), a4);
      a5 = fmaf(v2, bf2f((u16)(f2 >> 16)), a5);
      a6 = fmaf(v3, bf2f((u16)f3), a6);
      a7 = fmaf(v3, bf2f((u16)(f3 >> 16)), a7);
    }
    for (; j + 3 < n; j += 4) {          // two pairs (4 edges)
      int2 e0 = se[s + j + half];
      int2 e1 = se[s + j + 2 + half];
      u32 f0 = *(const u32*)(s1 + (size_t)e0.x * NH + fl * 2);
      u32 f1 = *(const u32*)(s1 + (size_t)e1.x * NH + fl * 2);
      float v0 = __int_as_float(e0.y), v1 = __int_as_float(e1.y);
      a0 = fmaf(v0, bf2f((u16)f0), a0);
      a1 = fmaf(v0, bf2f((u16)(f0 >> 16)), a1);
      a2 = fmaf(v1, bf2f((u16)f1), a2);
      a3 = fmaf(v1, bf2f((u16)(f1 >> 16)), a3);
    }
    for (; j < n; j += 2) {              // tail (1-3 edges)
      int idx = j + half;
      bool ok = idx < n;
      int2 e = se[s + (ok ? idx : 0)];
      float v = ok ? __int_as_float(e.y) : 0.f;
      u32 f = *(const u32*)(s1 + (size_t)e.x * NH + fl * 2);
      a0 = fmaf(v, bf2f((u16)f), a0);
      a1 = fmaf(v, bf2f((u16)(f >> 16)), a1);
    }
    float t0 = (a0 + a2) + (a4 + a6);
    float t1 = (a1 + a3) + (a5 + a7);
    t0 += __shfl_xor(t0, 32, 64);        // combine even/odd halves
    t1 += __shfl_xor(t1, 32, 64);
    hpack[i] = pack2(fmaxf(t0 + bias2.x, 0.f), fmaxf(t1 + bias2.y, 0.f));
  }
  __syncthreads();   // all waves done reading se -> safe to reuse as h blocks

  u16* hl = (u16*)se + (size_t)w * 16 * HPAD;
  if (half == 0) {
#pragma unroll
    for (int i = 0; i < 16; ++i) *(u32*)&hl[i * HPAD + fl * 2] = hpack[i];
  }

  const int l15 = lane & 15, l4 = lane >> 4;
  bf16x8 afr[2];
  afr[0] = *(const bf16x8*)&hl[l15 * HPAD + l4 * 8];
  afr[1] = *(const bf16x8*)&hl[l15 * HPAD + 32 + l4 * 8];

  f32x4 acc[3];
#pragma unroll
  for (int ct = 0; ct < 3; ++ct) acc[ct] = (f32x4){0.f, 0.f, 0.f, 0.f};
#pragma unroll
  for (int ct = 0; ct < 3; ++ct) {
#pragma unroll
    for (int kk = 0; kk < 2; ++kk) {
      u16x8 bw;
#pragma unroll
      for (int j = 0; j < 8; ++j)
        bw[j] = w10s[(kk * 32 + l4 * 8 + j) * W10PAD + ct * 16 + l15];
      acc[ct] = __builtin_amdgcn_mfma_f32_16x16x32_bf16(
          afr[kk], __builtin_bit_cast(bf16x8, bw), acc[ct], 0, 0, 0);
    }
  }
#pragma unroll
  for (int ct = 0; ct < 3; ++ct) {
    int c = ct * 16 + l15;
#pragma unroll
    for (int i = 0; i < 4; ++i) {
      int grow = bkt * BROWS + w * 16 + l4 * 4 + i;
      if (c < NC && grow < NND) s2[(size_t)grow * NC + c] = f2bf(acc[ct][i]);
    }
  }
}

// ---------------- SpMM2 half-bucket: half-wave pairs, 8-edge unroll + b10 + log_softmax ----------------
__global__ __launch_bounds__(512) void spmm2h_k(const int2* __restrict__ eb2,
                                                const int* __restrict__ rowoff,
                                                const int* __restrict__ rowcnt,
                                                const u16* __restrict__ s2,
                                                const float* __restrict__ b10,
                                                float* __restrict__ out) {
  __shared__ int2 se[BCAP];
  __shared__ int roff[128];
  __shared__ int rcnt[128];
  const int bh = blockIdx.x;
  const int bkt = bh >> 1, bhalf = bh & 1;
  const int t = threadIdx.x, w = t >> 6, lane = t & 63;
  const int half = lane >> 5, fl = lane & 31;
  const bool act = fl < (NC / 2);            // fl < 20
  const int fo = act ? fl * 2 : 0;           // in-bounds class-pair offset
  const int rowBase = bkt * BROWS + bhalf * 128;
  if (t < 128) {
    roff[t] = rowoff[rowBase + t];
    rcnt[t] = rowcnt[rowBase + t];
  }
  __syncthreads();
  const int base = roff[0];
  const int nE = min(roff[127] + rcnt[127] - base, BCAP);
  for (int i = t; i < nE; i += 512) se[i] = eb2[base + i];
  __syncthreads();

  const float2 bias2 = act ? *(const float2*)(b10 + fo) : make_float2(0.f, 0.f);
#pragma unroll 1
  for (int i = 0; i < 16; ++i) {
    int r8 = w * 16 + i;                     // 8 waves x 16 rows = 128
    int s = roff[r8] - base, n = rcnt[r8];
    float a0 = 0.f, a1 = 0.f, a2 = 0.f, a3 = 0.f;
    float a4 = 0.f, a5 = 0.f, a6 = 0.f, a7 = 0.f;
    int j = 0;
    for (; j + 7 < n; j += 8) {              // four pairs (8 edges)
      int2 e0 = se[s + j + half];
      int2 e1 = se[s + j + 2 + half];
      int2 e2 = se[s + j + 4 + half];
      int2 e3 = se[s + j + 6 + half];
      u32 f0 = *(const u32*)(s2 + (size_t)e0.x * NC + fo);
      u32 f1 = *(const u32*)(s2 + (size_t)e1.x * NC + fo);
      u32 f2 = *(const u32*)(s2 + (size_t)e2.x * NC + fo);
      u32 f3 = *(const u32*)(s2 + (size_t)e3.x * NC + fo);
      float v0 = __int_as_float(e0.y), v1 = __int_as_float(e1.y);
      float v2 = __int_as_float(e2.y), v3 = __int_as_float(e3.y);
      a0 = fmaf(v0, bf2f((u16)f0), a0);
      a1 = fmaf(v0, bf2f((u16)(f0 >> 16)), a1);
      a2 = fmaf(v1, bf2f((u16)f1), a2);
      a3 = fmaf(v1, bf2f((u16)(f1 >> 16)), a3);
      a4 = fmaf(v2, bf2f((u16)f2), a4);
      a5 = fmaf(v2, bf2f((u16)(f2 >> 16)), a5);
      a6 = fmaf(v3, bf2f((u16)f3), a6);
      a7 = fmaf(v3, bf2f((u16)(f3 >> 16)), a7);
    }
    for (; j + 3 < n; j += 4) {              // two pairs (4 edges)
      int2 e0 = se[s + j + half];
      int2 e1 = se[s + j + 2 + half];
      u32 f0 = *(const u32*)(s2 + (size_t)e0.x * NC + fo);
      u32 f1 = *(const u32*)(s2 + (size_t)e1.x * NC + fo);
      float v0 = __int_as_float(e0.y), v1 = __int_as_float(e1.y);
      a0 = fmaf(v0, bf2f((u16)f0), a0);
      a1 = fmaf(v0, bf2f((u16)(f0 >> 16)), a1);
      a2 = fmaf(v1, bf2f((u16)f1), a2);
      a3 = fmaf(v1, bf2f((u16)(f1 >> 16)), a3);
    }
    for (; j < n; j += 2) {                  // tail (1-3 edges)
      int idx = j + half;
      bool ok = idx < n;
      int2 e = se[s + (ok ? idx : 0)];
      float v = ok ? __int_as_float(e.y) : 0.f;
      u32 f = *(const u32*)(s2 + (size_t)e.x * NC + fo);
      a0 = fmaf(v, bf2f((u16)f), a0);
      a1 = fmaf(v, bf2f((u16)(f >> 16)), a1);
    }
    float t0 = (a0 + a2) + (a4 + a6);
    float t1 = (a1 + a3) + (a5 + a7);
    t0 += __shfl_xor(t0, 32, 64);            // combine even/odd halves
    t1 += __shfl_xor(t1, 32, 64);
    int grow = rowBase + r8;
    if (grow >= NND) continue;
    float v0 = act ? t0 + bias2.x : -INFINITY;
    float v1 = act ? t1 + bias2.y : -INFINITY;
    float m = fmaxf(v0, v1);
#pragma unroll
    for (int o = 16; o; o >>= 1) m = fmaxf(m, __shfl_xor(m, o, 64));  // within 32-group
    float e0 = act ? __expf(v0 - m) : 0.f;
    float e1 = act ? __expf(v1 - m) : 0.f;
    float ss = e0 + e1;
#pragma unroll
    for (int o = 16; o; o >>= 1) ss += __shfl_xor(ss, o, 64);
    float l = __logf(ss);
    if (act && half == 0)
      *(float2*)(out + (size_t)grow * NC + fo) = make_float2(v0 - m - l, v1 - m - l);
  }
}

extern "C" void kernel_launch(void* const* d_in, const int* in_sizes, int n_in,
                              void* d_out, int out_size, void* d_ws, size_t ws_size,
                              hipStream_t stream) {
  const float* x    = (const float*)d_in[0];
  const float* adj  = (const float*)d_in[1];
  const float* W1   = (const float*)d_in[2];
  const float* b1   = (const float*)d_in[3];
  const float* W10  = (const float*)d_in[4];
  const float* b10  = (const float*)d_in[5];
  const int*   erow = (const int*)d_in[6];
  const int*   ecol = (const int*)d_in[7];
  float* out = (float*)d_out;

  char* p = (char*)d_ws;
  u16*  s1  = (u16*)p;    p += (size_t)NND * NH * 2;        // 12.8 MB
  u16*  s2  = (u16*)p;    p += (size_t)NND * NC * 2;        // 8 MB
  u16*  w1t = (u16*)p;    p += (size_t)NF * NH * 2;         // 64 KB
  int2* eb1 = (int2*)p;   p += (size_t)NB * BCAP * 8;       // 15.2 MB
  int2* eb2 = (int2*)p;   p += (size_t)NB * BCAP * 8;       // 15.2 MB
  int* rowoff = (int*)p;  p += (size_t)NB * BROWS * 4;      // 400 KB
  int* rowcnt = (int*)p;  p += (size_t)NB * BROWS * 4;      // 400 KB
  int* gcursor = (int*)p;

  w1t_k<<<(NF * NH + 255) / 256, 256, 0, stream>>>(W1, w1t, gcursor);
  bscatter_k<<<NEB, 1024, 0, stream>>>(adj, erow, ecol, gcursor, eb1);

  gemm1_k<<<(NND + 127) / 128, 256, 0, stream>>>(x, w1t, s1);
  spmm1f_k<<<NB, 1024, 0, stream>>>(gcursor, eb1, s1, b1, W10, s2, eb2, rowoff, rowcnt);
  spmm2h_k<<<NB * 2, 512, 0, stream>>>(eb2, rowoff, rowcnt, s2, b10, out);
}

// Round 18
// 163.846 us; speedup vs baseline: 7.8924x; 1.0118x over previous
//
#include <hip/hip_runtime.h>

#define NND 100000
#define NE  1600000
#define NF  512
#define NH  64
#define NC  40

#define BROWS 256                          // rows per bucket
#define NB ((NND + BROWS - 1) / BROWS)     // 391 buckets
#define BCAP 4864                          // bucket capacity (mean 4096 + 12 sigma)
#define EPB 4096                           // edges per scatter block (4/thread)
#define NEB ((NE + EPB - 1) / EPB)         // 391 blocks
#define W10PAD 52                          // bf16 LDS pad for W10
#define HPAD 68                            // bf16 LDS pad for h block

typedef unsigned short u16;
typedef unsigned int   u32;
typedef __attribute__((ext_vector_type(8))) __bf16 bf16x8;
typedef __attribute__((ext_vector_type(8))) u16    u16x8;
typedef __attribute__((ext_vector_type(4))) float  f32x4;

__device__ __forceinline__ u16 f2bf(float f) {          // f32 -> bf16 RNE
  u32 u = __builtin_bit_cast(u32, f);
  u += 0x7FFFu + ((u >> 16) & 1u);
  return (u16)(u >> 16);
}
__device__ __forceinline__ u32 pack2(float a, float b) {
  return (u32)f2bf(a) | ((u32)f2bf(b) << 16);
}
__device__ __forceinline__ float bf2f(u16 h) {
  return __builtin_bit_cast(float, (u32)h << 16);
}
__device__ __forceinline__ bf16x8 pack8(const float4& a, const float4& b) {
  uint4 v;
  v.x = pack2(a.x, a.y); v.y = pack2(a.z, a.w);
  v.z = pack2(b.x, b.y); v.w = pack2(b.z, b.w);
  return __builtin_bit_cast(bf16x8, v);
}

// ---------------- W1 [512,64] f32 -> W1T [64,512] bf16 ; block 0 zeroes gcursor ----------------
__global__ __launch_bounds__(256) void w1t_k(const float* __restrict__ W1,
                                             u16* __restrict__ w1t,
                                             int* __restrict__ gcursor) {
  if (blockIdx.x == 0) {
    for (int i = threadIdx.x; i < NB; i += 256) gcursor[i] = 0;
  }
  int i = blockIdx.x * 256 + threadIdx.x;
  if (i >= NF * NH) return;
  int n = i >> 9, k = i & 511;
  w1t[i] = f2bf(W1[(size_t)k * NH + n]);
}

// ---------------- GEMM1 (bf16 MFMA): s1[N,64] = bf16(x[N,512] @ W1) ----------------
__global__ __launch_bounds__(256) void gemm1_k(const float* __restrict__ x,
                                               const u16* __restrict__ w1t,
                                               u16* __restrict__ out) {
  __shared__ u16 Bs[2][64][72];
  const int t = threadIdx.x, w = t >> 6, lane = t & 63;
  const int l15 = lane & 15, l4 = lane >> 4;
  const int rowBase = blockIdx.x * 128;
  const int r0 = rowBase + w * 32 + l15;
  const float* pa0 = x + (size_t)min(r0, NND - 1) * NF + l4 * 8;
  const float* pa1 = x + (size_t)min(r0 + 16, NND - 1) * NF + l4 * 8;

  f32x4 acc[2][4];
#pragma unroll
  for (int i = 0; i < 2; ++i)
#pragma unroll
    for (int j = 0; j < 4; ++j) acc[i][j] = (f32x4){0.f, 0.f, 0.f, 0.f};

  uint4  bR[2];
  float4 aR[2][2][2];   // [a0/a1][s][half]

  auto issueB = [&](int k0) {
#pragma unroll
    for (int i = 0; i < 2; ++i) {
      int c = t + i * 256;
      bR[i] = *(const uint4*)(w1t + (size_t)(c >> 3) * NF + k0 + (c & 7) * 8);
    }
  };
  auto issueA = [&](int k0) {
#pragma unroll
    for (int s = 0; s < 2; ++s) {
      const float* q0 = pa0 + k0 + s * 32;
      const float* q1 = pa1 + k0 + s * 32;
      aR[0][s][0] = *(const float4*)(q0);
      aR[0][s][1] = *(const float4*)(q0 + 4);
      aR[1][s][0] = *(const float4*)(q1);
      aR[1][s][1] = *(const float4*)(q1 + 4);
    }
  };

  issueB(0);
  issueA(0);
  for (int it = 0; it < 8; ++it) {
    const int b = it & 1;
#pragma unroll
    for (int i = 0; i < 2; ++i) {          // stage B tile
      int c = t + i * 256;
      *(uint4*)&Bs[b][c >> 3][(c & 7) * 8] = bR[i];
    }
    bf16x8 fa0[2], fa1[2];
#pragma unroll
    for (int s = 0; s < 2; ++s) {
      fa0[s] = pack8(aR[0][s][0], aR[0][s][1]);
      fa1[s] = pack8(aR[1][s][0], aR[1][s][1]);
    }
    if (it < 7) { issueB((it + 1) * 64); issueA((it + 1) * 64); }
    __syncthreads();
#pragma unroll
    for (int s = 0; s < 2; ++s) {
#pragma unroll
      for (int ct = 0; ct < 4; ++ct) {
        bf16x8 bb = *(const bf16x8*)&Bs[b][ct * 16 + l15][s * 32 + l4 * 8];
        acc[0][ct] = __builtin_amdgcn_mfma_f32_16x16x32_bf16(fa0[s], bb, acc[0][ct], 0, 0, 0);
        acc[1][ct] = __builtin_amdgcn_mfma_f32_16x16x32_bf16(fa1[s], bb, acc[1][ct], 0, 0, 0);
      }
    }
  }

#pragma unroll
  for (int rt = 0; rt < 2; ++rt)
#pragma unroll
    for (int ct = 0; ct < 4; ++ct)
#pragma unroll
      for (int i = 0; i < 4; ++i) {
        int row = rowBase + w * 32 + rt * 16 + l4 * 4 + i;   // C/D: col=lane&15, row=(lane>>4)*4+reg
        if (row < NND) out[(size_t)row * NH + ct * 16 + l15] = f2bf(acc[rt][ct][i]);
      }
}

// ---------------- bucket scatter with block-local LDS reorder ----------------
// Edges binned+ranked in LDS, grouped by bin in sedg[], then copied out with
// consecutive threads writing consecutive addresses within each bin run ->
// L2 merges full lines (fixes the 8x write amplification of rank-scattered stores).
// eb1 entry: (col<<8 | row&255, val); bucket b owns eb1[b*BCAP .. b*BCAP+count)
__global__ __launch_bounds__(1024) void bscatter_k(const float* __restrict__ vals,
                                                   const int* __restrict__ rows,
                                                   const int* __restrict__ cols,
                                                   int* __restrict__ gcursor,
                                                   int2* __restrict__ eb1) {
  __shared__ int2 sedg[EPB];    // 32 KB
  __shared__ u16  sbin[EPB];    // 8 KB
  __shared__ int cnt[NB];
  __shared__ int lstart[NB];
  __shared__ int gbase[NB];
  __shared__ int wsum[7];
  const int t = threadIdx.x;
  for (int i = t; i < NB; i += 1024) cnt[i] = 0;
  __syncthreads();
  const int gb = blockIdx.x * EPB;
  int bin[4], rnk[4], rr[4], cc[4];
  float vv[4];
#pragma unroll
  for (int k = 0; k < 4; ++k) {
    int i = gb + t + k * 1024;
    if (i < NE) {
      rr[k] = rows[i]; cc[k] = cols[i]; vv[k] = vals[i];
      bin[k] = rr[k] >> 8;
      rnk[k] = atomicAdd(&cnt[bin[k]], 1);
    } else bin[k] = -1;
  }
  __syncthreads();
  // exclusive scan of cnt[0..NB) -> lstart; allocate global runs -> gbase
  int c0 = 0, inc = 0;
  if (t < 448) {                        // 7 waves cover 391 bins (inactive tail = 0)
    c0 = (t < NB) ? cnt[t] : 0;
    inc = c0;
#pragma unroll
    for (int off = 1; off < 64; off <<= 1) {
      int u = __shfl_up(inc, off, 64);
      if ((t & 63) >= off) inc += u;
    }
    if ((t & 63) == 63) wsum[t >> 6] = inc;
  }
  __syncthreads();
  if (t < NB) {
    int pre = 0;
#pragma unroll
    for (int k = 0; k < 7; ++k) pre += (k < (t >> 6)) ? wsum[k] : 0;
    lstart[t] = pre + inc - c0;
    if (c0) gbase[t] = t * BCAP + atomicAdd(&gcursor[t], c0);
  }
  __syncthreads();
  // group edges by bin in LDS
#pragma unroll
  for (int k = 0; k < 4; ++k) {
    if (bin[k] >= 0) {
      int p = lstart[bin[k]] + rnk[k];
      sedg[p] = make_int2((int)(((u32)cc[k] << 8) | (u32)(rr[k] & 255)),
                          __float_as_int(vv[k]));
      sbin[p] = (u16)bin[k];
    }
  }
  __syncthreads();
  // copy out: lane-consecutive elements -> address-consecutive within runs
  const int nE = min(EPB, NE - gb);
#pragma unroll
  for (int k = 0; k < 4; ++k) {
    int i = t + k * 1024;
    if (i < nE) {
      int b = sbin[i];
      eb1[gbase[b] + (i - lstart[b])] = sedg[i];
    }
  }
}

// ---------------- SpMM1 fused sort+gather+GEMM2; exports sorted edges + rowoff/rowcnt ----------------
// Gather: half-wave edge pairs, 4 pairs (8 edges) per iteration for MLP depth 4.
__global__ __launch_bounds__(1024) void spmm1f_k(const int* __restrict__ gcursor,
                                                 const int2* __restrict__ eb1,
                                                 const u16* __restrict__ s1,
                                                 const float* __restrict__ b1,
                                                 const float* __restrict__ W10,
                                                 u16* __restrict__ s2,
                                                 int2* __restrict__ eb2,
                                                 int* __restrict__ rowoff,
                                                 int* __restrict__ rowcnt) {
  __shared__ int2 se[BCAP];            // 38.9 KB; reused as per-wave h blocks after gather
  __shared__ u16 w10s[64 * W10PAD];    // 6.7 KB bf16 W10 [k][c]
  __shared__ int cnt[BROWS];
  __shared__ int sc[BROWS];
  __shared__ int wsum[4];
  const int bkt = blockIdx.x, t = threadIdx.x;
  const int w = t >> 6, lane = t & 63;
  const int half = lane >> 5, fl = lane & 31;   // feature pair index (features 2fl, 2fl+1)
  const int nE = min(gcursor[bkt], BCAP);
  const int beg = bkt * BCAP;
  for (int i = t; i < 64 * W10PAD; i += 1024) {
    int k = i / W10PAD, c = i - k * W10PAD;
    w10s[i] = (c < NC) ? f2bf(W10[k * NC + c]) : (u16)0;
  }
  if (t < BROWS) cnt[t] = 0;
  __syncthreads();
  int2 mye[5]; int myrow[5], myrank[5];
#pragma unroll
  for (int k = 0; k < 5; ++k) {
    int i = t + k * 1024;
    myrow[k] = -1;
    if (i < nE) {
      int2 e = eb1[beg + i];
      mye[k] = e;
      myrow[k] = e.x & 255;
      myrank[k] = atomicAdd(&cnt[myrow[k]], 1);
    }
  }
  __syncthreads();
  int c0 = 0, inc = 0;
  if (t < BROWS) {
    c0 = cnt[t]; inc = c0;
#pragma unroll
    for (int off = 1; off < 64; off <<= 1) {
      int u = __shfl_up(inc, off, 64);
      if ((t & 63) >= off) inc += u;
    }
    if ((t & 63) == 63) wsum[t >> 6] = inc;
  }
  __syncthreads();
  if (t < BROWS) {
    int pre = 0;
#pragma unroll
    for (int k = 0; k < 4; ++k) pre += (k < (t >> 6)) ? wsum[k] : 0;
    int ex = pre + inc - c0;
    sc[t] = ex;
    rowoff[bkt * BROWS + t] = beg + ex;      // absolute eb2 offset for spmm2
    rowcnt[bkt * BROWS + t] = c0;            // per-row count for spmm2
  }
  __syncthreads();
#pragma unroll
  for (int k = 0; k < 5; ++k)
    if (myrow[k] >= 0)
      se[sc[myrow[k]] + myrank[k]] = make_int2((int)((u32)mye[k].x >> 8), mye[k].y);
  __syncthreads();

  // export sorted edges (coalesced) so spmm2 skips the sort
#pragma unroll
  for (int k = 0; k < 5; ++k) {
    int i = t + k * 1024;
    if (i < nE) eb2[beg + i] = se[i];
  }

  // gather: wave w owns rows w*16..w*16+15; half-wave pairs, 8-edge unroll
  const float2 bias2 = *(const float2*)(b1 + fl * 2);
  u32 hpack[16];
#pragma unroll 1
  for (int i = 0; i < 16; ++i) {
    int r8 = w * 16 + i;
    int s = sc[r8], n = cnt[r8];
    float a0 = 0.f, a1 = 0.f, a2 = 0.f, a3 = 0.f;
    float a4 = 0.f, a5 = 0.f, a6 = 0.f, a7 = 0.f;
    int j = 0;
    for (; j + 7 < n; j += 8) {          // four pairs (8 edges), MLP depth 4
      int2 e0 = se[s + j + half];
      int2 e1 = se[s + j + 2 + half];
      int2 e2 = se[s + j + 4 + half];
      int2 e3 = se[s + j + 6 + half];
      u32 f0 = *(const u32*)(s1 + (size_t)e0.x * NH + fl * 2);
      u32 f1 = *(const u32*)(s1 + (size_t)e1.x * NH + fl * 2);
      u32 f2 = *(const u32*)(s1 + (size_t)e2.x * NH + fl * 2);
      u32 f3 = *(const u32*)(s1 + (size_t)e3.x * NH + fl * 2);
      float v0 = __int_as_float(e0.y), v1 = __int_as_float(e1.y);
      float v2 = __int_as_float(e2.y), v3 = __int_as_float(e3.y);
      a0 = fmaf(v0, bf2f((u16)f0), a0);
      a1 = fmaf(v0, bf2f((u16)(f0 >> 16)), a1);
      a2 = fmaf(v1, bf2f((u16)f1), a2);
      a3 = fmaf(v1, bf2f((u16)(f1 >> 16)), a3);
      a4 = fmaf(v2, bf2f((u16)f2), a4);
      a5 = fmaf(v2, bf2f((u16)(f2 >> 16)), a5);
      a6 = fmaf(v3, bf2f((u16)f3), a6);
      a7 = fmaf(v3, bf2f((u16)(f3 >> 16)), a7);
    }
    for (; j + 3 < n; j += 4) {          // two pairs (4 edges)
      int2 e0 = se[s + j + half];
      int2 e1 = se[s + j + 2 + half];
      u32 f0 = *(const u32*)(s1 + (size_t)e0.x * NH + fl * 2);
      u32 f1 = *(const u32*)(s1 + (size_t)e1.x * NH + fl * 2);
      float v0 = __int_as_float(e0.y), v1 = __int_as_float(e1.y);
      a0 = fmaf(v0, bf2f((u16)f0), a0);
      a1 = fmaf(v0, bf2f((u16)(f0 >> 16)), a1);
      a2 = fmaf(v1, bf2f((u16)f1), a2);
      a3 = fmaf(v1, bf2f((u16)(f1 >> 16)), a3);
    }
    for (; j < n; j += 2) {              // tail (1-3 edges)
      int idx = j + half;
      bool ok = idx < n;
      int2 e = se[s + (ok ? idx : 0)];
      float v = ok ? __int_as_float(e.y) : 0.f;
      u32 f = *(const u32*)(s1 + (size_t)e.x * NH + fl * 2);
      a0 = fmaf(v, bf2f((u16)f), a0);
      a1 = fmaf(v, bf2f((u16)(f >> 16)), a1);
    }
    float t0 = (a0 + a2) + (a4 + a6);
    float t1 = (a1 + a3) + (a5 + a7);
    t0 += __shfl_xor(t0, 32, 64);        // combine even/odd halves
    t1 += __shfl_xor(t1, 32, 64);
    hpack[i] = pack2(fmaxf(t0 + bias2.x, 0.f), fmaxf(t1 + bias2.y, 0.f));
  }
  __syncthreads();   // all waves done reading se -> safe to reuse as h blocks

  u16* hl = (u16*)se + (size_t)w * 16 * HPAD;
  if (half == 0) {
#pragma unroll
    for (int i = 0; i < 16; ++i) *(u32*)&hl[i * HPAD + fl * 2] = hpack[i];
  }

  const int l15 = lane & 15, l4 = lane >> 4;
  bf16x8 afr[2];
  afr[0] = *(const bf16x8*)&hl[l15 * HPAD + l4 * 8];
  afr[1] = *(const bf16x8*)&hl[l15 * HPAD + 32 + l4 * 8];

  f32x4 acc[3];
#pragma unroll
  for (int ct = 0; ct < 3; ++ct) acc[ct] = (f32x4){0.f, 0.f, 0.f, 0.f};
#pragma unroll
  for (int ct = 0; ct < 3; ++ct) {
#pragma unroll
    for (int kk = 0; kk < 2; ++kk) {
      u16x8 bw;
#pragma unroll
      for (int j = 0; j < 8; ++j)
        bw[j] = w10s[(kk * 32 + l4 * 8 + j) * W10PAD + ct * 16 + l15];
      acc[ct] = __builtin_amdgcn_mfma_f32_16x16x32_bf16(
          afr[kk], __builtin_bit_cast(bf16x8, bw), acc[ct], 0, 0, 0);
    }
  }
#pragma unroll
  for (int ct = 0; ct < 3; ++ct) {
    int c = ct * 16 + l15;
#pragma unroll
    for (int i = 0; i < 4; ++i) {
      int grow = bkt * BROWS + w * 16 + l4 * 4 + i;
      if (c < NC && grow < NND) s2[(size_t)grow * NC + c] = f2bf(acc[ct][i]);
    }
  }
}

// ---------------- SpMM2 half-bucket: half-wave pairs, 8-edge unroll + b10 + log_softmax ----------------
__global__ __launch_bounds__(512) void spmm2h_k(const int2* __restrict__ eb2,
                                                const int* __restrict__ rowoff,
                                                const int* __restrict__ rowcnt,
                                                const u16* __restrict__ s2,
                                                const float* __restrict__ b10,
                                                float* __restrict__ out) {
  __shared__ int2 se[BCAP];
  __shared__ int roff[128];
  __shared__ int rcnt[128];
  const int bh = blockIdx.x;
  const int bkt = bh >> 1, bhalf = bh & 1;
  const int t = threadIdx.x, w = t >> 6, lane = t & 63;
  const int half = lane >> 5, fl = lane & 31;
  const bool act = fl < (NC / 2);            // fl < 20
  const int fo = act ? fl * 2 : 0;           // in-bounds class-pair offset
  const int rowBase = bkt * BROWS + bhalf * 128;
  if (t < 128) {
    roff[t] = rowoff[rowBase + t];
    rcnt[t] = rowcnt[rowBase + t];
  }
  __syncthreads();
  const int base = roff[0];
  const int nE = min(roff[127] + rcnt[127] - base, BCAP);
  for (int i = t; i < nE; i += 512) se[i] = eb2[base + i];
  __syncthreads();

  const float2 bias2 = act ? *(const float2*)(b10 + fo) : make_float2(0.f, 0.f);
#pragma unroll 1
  for (int i = 0; i < 16; ++i) {
    int r8 = w * 16 + i;                     // 8 waves x 16 rows = 128
    int s = roff[r8] - base, n = rcnt[r8];
    float a0 = 0.f, a1 = 0.f, a2 = 0.f, a3 = 0.f;
    float a4 = 0.f, a5 = 0.f, a6 = 0.f, a7 = 0.f;
    int j = 0;
    for (; j + 7 < n; j += 8) {              // four pairs (8 edges)
      int2 e0 = se[s + j + half];
      int2 e1 = se[s + j + 2 + half];
      int2 e2 = se[s + j + 4 + half];
      int2 e3 = se[s + j + 6 + half];
      u32 f0 = *(const u32*)(s2 + (size_t)e0.x * NC + fo);
      u32 f1 = *(const u32*)(s2 + (size_t)e1.x * NC + fo);
      u32 f2 = *(const u32*)(s2 + (size_t)e2.x * NC + fo);
      u32 f3 = *(const u32*)(s2 + (size_t)e3.x * NC + fo);
      float v0 = __int_as_float(e0.y), v1 = __int_as_float(e1.y);
      float v2 = __int_as_float(e2.y), v3 = __int_as_float(e3.y);
      a0 = fmaf(v0, bf2f((u16)f0), a0);
      a1 = fmaf(v0, bf2f((u16)(f0 >> 16)), a1);
      a2 = fmaf(v1, bf2f((u16)f1), a2);
      a3 = fmaf(v1, bf2f((u16)(f1 >> 16)), a3);
      a4 = fmaf(v2, bf2f((u16)f2), a4);
      a5 = fmaf(v2, bf2f((u16)(f2 >> 16)), a5);
      a6 = fmaf(v3, bf2f((u16)f3), a6);
      a7 = fmaf(v3, bf2f((u16)(f3 >> 16)), a7);
    }
    for (; j + 3 < n; j += 4) {              // two pairs (4 edges)
      int2 e0 = se[s + j + half];
      int2 e1 = se[s + j + 2 + half];
      u32 f0 = *(const u32*)(s2 + (size_t)e0.x * NC + fo);
      u32 f1 = *(const u32*)(s2 + (size_t)e1.x * NC + fo);
      float v0 = __int_as_float(e0.y), v1 = __int_as_float(e1.y);
      a0 = fmaf(v0, bf2f((u16)f0), a0);
      a1 = fmaf(v0, bf2f((u16)(f0 >> 16)), a1);
      a2 = fmaf(v1, bf2f((u16)f1), a2);
      a3 = fmaf(v1, bf2f((u16)(f1 >> 16)), a3);
    }
    for (; j < n; j += 2) {                  // tail (1-3 edges)
      int idx = j + half;
      bool ok = idx < n;
      int2 e = se[s + (ok ? idx : 0)];
      float v = ok ? __int_as_float(e.y) : 0.f;
      u32 f = *(const u32*)(s2 + (size_t)e.x * NC + fo);
      a0 = fmaf(v, bf2f((u16)f), a0);
      a1 = fmaf(v, bf2f((u16)(f >> 16)), a1);
    }
    float t0 = (a0 + a2) + (a4 + a6);
    float t1 = (a1 + a3) + (a5 + a7);
    t0 += __shfl_xor(t0, 32, 64);            // combine even/odd halves
    t1 += __shfl_xor(t1, 32, 64);
    int grow = rowBase + r8;
    if (grow >= NND) continue;
    float v0 = act ? t0 + bias2.x : -INFINITY;
    float v1 = act ? t1 + bias2.y : -INFINITY;
    float m = fmaxf(v0, v1);
#pragma unroll
    for (int o = 16; o; o >>= 1) m = fmaxf(m, __shfl_xor(m, o, 64));  // within 32-group
    float e0 = act ? __expf(v0 - m) : 0.f;
    float e1 = act ? __expf(v1 - m) : 0.f;
    float ss = e0 + e1;
#pragma unroll
    for (int o = 16; o; o >>= 1) ss += __shfl_xor(ss, o, 64);
    float l = __logf(ss);
    if (act && half == 0)
      *(float2*)(out + (size_t)grow * NC + fo) = make_float2(v0 - m - l, v1 - m - l);
  }
}

extern "C" void kernel_launch(void* const* d_in, const int* in_sizes, int n_in,
                              void* d_out, int out_size, void* d_ws, size_t ws_size,
                              hipStream_t stream) {
  const float* x    = (const float*)d_in[0];
  const float* adj  = (const float*)d_in[1];
  const float* W1   = (const float*)d_in[2];
  const float* b1   = (const float*)d_in[3];
  const float* W10  = (const float*)d_in[4];
  const float* b10  = (const float*)d_in[5];
  const int*   erow = (const int*)d_in[6];
  const int*   ecol = (const int*)d_in[7];
  float* out = (float*)d_out;

  char* p = (char*)d_ws;
  u16*  s1  = (u16*)p;    p += (size_t)NND * NH * 2;        // 12.8 MB
  u16*  s2  = (u16*)p;    p += (size_t)NND * NC * 2;        // 8 MB
  u16*  w1t = (u16*)p;    p += (size_t)NF * NH * 2;         // 64 KB
  int2* eb1 = (int2*)p;   p += (size_t)NB * BCAP * 8;       // 15.2 MB
  int2* eb2 = (int2*)p;   p += (size_t)NB * BCAP * 8;       // 15.2 MB
  int* rowoff = (int*)p;  p += (size_t)NB * BROWS * 4;      // 400 KB
  int* rowcnt = (int*)p;  p += (size_t)NB * BROWS * 4;      // 400 KB
  int* gcursor = (int*)p;

  w1t_k<<<(NF * NH + 255) / 256, 256, 0, stream>>>(W1, w1t, gcursor);
  bscatter_k<<<NEB, 1024, 0, stream>>>(adj, erow, ecol, gcursor, eb1);

  gemm1_k<<<(NND + 127) / 128, 256, 0, stream>>>(x, w1t, s1);
  spmm1f_k<<<NB, 1024, 0, stream>>>(gcursor, eb1, s1, b1, W10, s2, eb2, rowoff, rowcnt);
  spmm2h_k<<<NB * 2, 512, 0, stream>>>(eb2, rowoff, rowcnt, s2, b10, out);
}

// Round 19
// 163.780 us; speedup vs baseline: 7.8956x; 1.0004x over previous
//
#include <hip/hip_runtime.h>

#define NND 100000
#define NE  1600000
#define NF  512
#define NH  64
#define NC  40

#define BROWS 256                          // rows per bucket
#define NB ((NND + BROWS - 1) / BROWS)     // 391 buckets
#define BCAP 4864                          // bucket capacity (mean 4096 + 12 sigma)
#define EPB 4096                           // edges per scatter block (4/thread)
#define NEB ((NE + EPB - 1) / EPB)         // 391 blocks
#define W10PAD 52                          // bf16 LDS pad for W10
#define HPAD 68                            // bf16 LDS pad for h block

typedef unsigned short u16;
typedef unsigned int   u32;
typedef __attribute__((ext_vector_type(8))) __bf16 bf16x8;
typedef __attribute__((ext_vector_type(8))) u16    u16x8;
typedef __attribute__((ext_vector_type(4))) float  f32x4;

__device__ __forceinline__ u16 f2bf(float f) {          // f32 -> bf16 RNE
  u32 u = __builtin_bit_cast(u32, f);
  u += 0x7FFFu + ((u >> 16) & 1u);
  return (u16)(u >> 16);
}
__device__ __forceinline__ u32 pack2(float a, float b) {
  return (u32)f2bf(a) | ((u32)f2bf(b) << 16);
}
__device__ __forceinline__ float bf2f(u16 h) {
  return __builtin_bit_cast(float, (u32)h << 16);
}
__device__ __forceinline__ bf16x8 pack8(const float4& a, const float4& b) {
  uint4 v;
  v.x = pack2(a.x, a.y); v.y = pack2(a.z, a.w);
  v.z = pack2(b.x, b.y); v.w = pack2(b.z, b.w);
  return __builtin_bit_cast(bf16x8, v);
}

// ---------------- W1 [512,64] f32 -> W1T [64,512] bf16 ; block 0 zeroes gcursor ----------------
__global__ __launch_bounds__(256) void w1t_k(const float* __restrict__ W1,
                                             u16* __restrict__ w1t,
                                             int* __restrict__ gcursor) {
  if (blockIdx.x == 0) {
    for (int i = threadIdx.x; i < NB; i += 256) gcursor[i] = 0;
  }
  int i = blockIdx.x * 256 + threadIdx.x;
  if (i >= NF * NH) return;
  int n = i >> 9, k = i & 511;
  w1t[i] = f2bf(W1[(size_t)k * NH + n]);
}

// ---------------- GEMM1 (bf16 MFMA): s1[N,64] = bf16(x[N,512] @ W1) ----------------
__global__ __launch_bounds__(256) void gemm1_k(const float* __restrict__ x,
                                               const u16* __restrict__ w1t,
                                               u16* __restrict__ out) {
  __shared__ u16 Bs[2][64][72];
  const int t = threadIdx.x, w = t >> 6, lane = t & 63;
  const int l15 = lane & 15, l4 = lane >> 4;
  const int rowBase = blockIdx.x * 128;
  const int r0 = rowBase + w * 32 + l15;
  const float* pa0 = x + (size_t)min(r0, NND - 1) * NF + l4 * 8;
  const float* pa1 = x + (size_t)min(r0 + 16, NND - 1) * NF + l4 * 8;

  f32x4 acc[2][4];
#pragma unroll
  for (int i = 0; i < 2; ++i)
#pragma unroll
    for (int j = 0; j < 4; ++j) acc[i][j] = (f32x4){0.f, 0.f, 0.f, 0.f};

  uint4  bR[2];
  float4 aR[2][2][2];   // [a0/a1][s][half]

  auto issueB = [&](int k0) {
#pragma unroll
    for (int i = 0; i < 2; ++i) {
      int c = t + i * 256;
      bR[i] = *(const uint4*)(w1t + (size_t)(c >> 3) * NF + k0 + (c & 7) * 8);
    }
  };
  auto issueA = [&](int k0) {
#pragma unroll
    for (int s = 0; s < 2; ++s) {
      const float* q0 = pa0 + k0 + s * 32;
      const float* q1 = pa1 + k0 + s * 32;
      aR[0][s][0] = *(const float4*)(q0);
      aR[0][s][1] = *(const float4*)(q0 + 4);
      aR[1][s][0] = *(const float4*)(q1);
      aR[1][s][1] = *(const float4*)(q1 + 4);
    }
  };

  issueB(0);
  issueA(0);
  for (int it = 0; it < 8; ++it) {
    const int b = it & 1;
#pragma unroll
    for (int i = 0; i < 2; ++i) {          // stage B tile
      int c = t + i * 256;
      *(uint4*)&Bs[b][c >> 3][(c & 7) * 8] = bR[i];
    }
    bf16x8 fa0[2], fa1[2];
#pragma unroll
    for (int s = 0; s < 2; ++s) {
      fa0[s] = pack8(aR[0][s][0], aR[0][s][1]);
      fa1[s] = pack8(aR[1][s][0], aR[1][s][1]);
    }
    if (it < 7) { issueB((it + 1) * 64); issueA((it + 1) * 64); }
    __syncthreads();
#pragma unroll
    for (int s = 0; s < 2; ++s) {
#pragma unroll
      for (int ct = 0; ct < 4; ++ct) {
        bf16x8 bb = *(const bf16x8*)&Bs[b][ct * 16 + l15][s * 32 + l4 * 8];
        acc[0][ct] = __builtin_amdgcn_mfma_f32_16x16x32_bf16(fa0[s], bb, acc[0][ct], 0, 0, 0);
        acc[1][ct] = __builtin_amdgcn_mfma_f32_16x16x32_bf16(fa1[s], bb, acc[1][ct], 0, 0, 0);
      }
    }
  }

#pragma unroll
  for (int rt = 0; rt < 2; ++rt)
#pragma unroll
    for (int ct = 0; ct < 4; ++ct)
#pragma unroll
      for (int i = 0; i < 4; ++i) {
        int row = rowBase + w * 32 + rt * 16 + l4 * 4 + i;   // C/D: col=lane&15, row=(lane>>4)*4+reg
        if (row < NND) out[(size_t)row * NH + ct * 16 + l15] = f2bf(acc[rt][ct][i]);
      }
}

// ---------------- bucket scatter: dual privatized histograms + vectorized loads ----------------
// Waves 0-7 rank into cnt2[0][.], waves 8-15 into cnt2[1][.] -> same-address atomic
// serialization halves. Edges loaded as int4/float4 (4 consecutive per thread).
// LDS reorder then run-contiguous copy-out (merged global writes).
// eb1 entry: (col<<8 | row&255, val); bucket b owns eb1[b*BCAP .. b*BCAP+count)
__global__ __launch_bounds__(1024) void bscatter_k(const float* __restrict__ vals,
                                                   const int* __restrict__ rows,
                                                   const int* __restrict__ cols,
                                                   int* __restrict__ gcursor,
                                                   int2* __restrict__ eb1) {
  __shared__ int2 sedg[EPB];    // 32 KB
  __shared__ u16  sbin[EPB];    // 8 KB
  __shared__ int cnt2[2][NB];   // privatized histograms
  __shared__ int lstart[NB];
  __shared__ int gbase[NB];
  __shared__ int wsum[7];
  const int t = threadIdx.x;
  const int hg = t >> 9;        // histogram group: 0 (waves 0-7) / 1 (waves 8-15)
  for (int i = t; i < 2 * NB; i += 1024) ((int*)cnt2)[i] = 0;
  __syncthreads();
  const int gb = blockIdx.x * EPB;
  const int base4 = gb + t * 4;
  int bin[4], rnk[4];
  int4 rr4, cc4;
  float4 vv4;
  bool ok = base4 < NE;         // NE and tail are multiples of 4 -> all-or-none
  if (ok) {
    rr4 = *(const int4*)(rows + base4);
    cc4 = *(const int4*)(cols + base4);
    vv4 = *(const float4*)(vals + base4);
    bin[0] = rr4.x >> 8; bin[1] = rr4.y >> 8;
    bin[2] = rr4.z >> 8; bin[3] = rr4.w >> 8;
#pragma unroll
    for (int k = 0; k < 4; ++k) rnk[k] = atomicAdd(&cnt2[hg][bin[k]], 1);
  } else {
    bin[0] = bin[1] = bin[2] = bin[3] = -1;
  }
  __syncthreads();
  // merged exclusive scan of c0 = cnt2[0]+cnt2[1] -> lstart; allocate global runs
  int c0 = 0, inc = 0;
  if (t < 448) {                // 7 waves cover 391 bins (inactive tail = 0)
    c0 = (t < NB) ? cnt2[0][t] + cnt2[1][t] : 0;
    inc = c0;
#pragma unroll
    for (int off = 1; off < 64; off <<= 1) {
      int u = __shfl_up(inc, off, 64);
      if ((t & 63) >= off) inc += u;
    }
    if ((t & 63) == 63) wsum[t >> 6] = inc;
  }
  __syncthreads();
  if (t < NB) {
    int pre = 0;
#pragma unroll
    for (int k = 0; k < 7; ++k) pre += (k < (t >> 6)) ? wsum[k] : 0;
    lstart[t] = pre + inc - c0;
    if (c0) gbase[t] = t * BCAP + atomicAdd(&gcursor[t], c0);
  }
  __syncthreads();
  // group edges by bin in LDS (group-1 ranks offset by group-0 counts)
  if (ok) {
    int rr[4] = {rr4.x, rr4.y, rr4.z, rr4.w};
    int cc[4] = {cc4.x, cc4.y, cc4.z, cc4.w};
    float vv[4] = {vv4.x, vv4.y, vv4.z, vv4.w};
#pragma unroll
    for (int k = 0; k < 4; ++k) {
      int p = lstart[bin[k]] + (hg ? cnt2[0][bin[k]] : 0) + rnk[k];
      sedg[p] = make_int2((int)(((u32)cc[k] << 8) | (u32)(rr[k] & 255)),
                          __float_as_int(vv[k]));
      sbin[p] = (u16)bin[k];
    }
  }
  __syncthreads();
  // copy out: lane-consecutive elements -> address-consecutive within runs
  const int nE = min(EPB, NE - gb);
#pragma unroll
  for (int k = 0; k < 4; ++k) {
    int i = t + k * 1024;
    if (i < nE) {
      int b = sbin[i];
      eb1[gbase[b] + (i - lstart[b])] = sedg[i];
    }
  }
}

// ---------------- SpMM1 fused sort+gather+GEMM2; exports sorted edges + rowoff/rowcnt ----------------
// Gather: half-wave edge pairs, 4 pairs (8 edges) per iteration for MLP depth 4.
__global__ __launch_bounds__(1024) void spmm1f_k(const int* __restrict__ gcursor,
                                                 const int2* __restrict__ eb1,
                                                 const u16* __restrict__ s1,
                                                 const float* __restrict__ b1,
                                                 const float* __restrict__ W10,
                                                 u16* __restrict__ s2,
                                                 int2* __restrict__ eb2,
                                                 int* __restrict__ rowoff,
                                                 int* __restrict__ rowcnt) {
  __shared__ int2 se[BCAP];            // 38.9 KB; reused as per-wave h blocks after gather
  __shared__ u16 w10s[64 * W10PAD];    // 6.7 KB bf16 W10 [k][c]
  __shared__ int cnt[BROWS];
  __shared__ int sc[BROWS];
  __shared__ int wsum[4];
  const int bkt = blockIdx.x, t = threadIdx.x;
  const int w = t >> 6, lane = t & 63;
  const int half = lane >> 5, fl = lane & 31;   // feature pair index (features 2fl, 2fl+1)
  const int nE = min(gcursor[bkt], BCAP);
  const int beg = bkt * BCAP;
  for (int i = t; i < 64 * W10PAD; i += 1024) {
    int k = i / W10PAD, c = i - k * W10PAD;
    w10s[i] = (c < NC) ? f2bf(W10[k * NC + c]) : (u16)0;
  }
  if (t < BROWS) cnt[t] = 0;
  __syncthreads();
  int2 mye[5]; int myrow[5], myrank[5];
#pragma unroll
  for (int k = 0; k < 5; ++k) {
    int i = t + k * 1024;
    myrow[k] = -1;
    if (i < nE) {
      int2 e = eb1[beg + i];
      mye[k] = e;
      myrow[k] = e.x & 255;
      myrank[k] = atomicAdd(&cnt[myrow[k]], 1);
    }
  }
  __syncthreads();
  int c0 = 0, inc = 0;
  if (t < BROWS) {
    c0 = cnt[t]; inc = c0;
#pragma unroll
    for (int off = 1; off < 64; off <<= 1) {
      int u = __shfl_up(inc, off, 64);
      if ((t & 63) >= off) inc += u;
    }
    if ((t & 63) == 63) wsum[t >> 6] = inc;
  }
  __syncthreads();
  if (t < BROWS) {
    int pre = 0;
#pragma unroll
    for (int k = 0; k < 4; ++k) pre += (k < (t >> 6)) ? wsum[k] : 0;
    int ex = pre + inc - c0;
    sc[t] = ex;
    rowoff[bkt * BROWS + t] = beg + ex;      // absolute eb2 offset for spmm2
    rowcnt[bkt * BROWS + t] = c0;            // per-row count for spmm2
  }
  __syncthreads();
#pragma unroll
  for (int k = 0; k < 5; ++k)
    if (myrow[k] >= 0)
      se[sc[myrow[k]] + myrank[k]] = make_int2((int)((u32)mye[k].x >> 8), mye[k].y);
  __syncthreads();

  // export sorted edges (coalesced) so spmm2 skips the sort
#pragma unroll
  for (int k = 0; k < 5; ++k) {
    int i = t + k * 1024;
    if (i < nE) eb2[beg + i] = se[i];
  }

  // gather: wave w owns rows w*16..w*16+15; half-wave pairs, 8-edge unroll
  const float2 bias2 = *(const float2*)(b1 + fl * 2);
  u32 hpack[16];
#pragma unroll 1
  for (int i = 0; i < 16; ++i) {
    int r8 = w * 16 + i;
    int s = sc[r8], n = cnt[r8];
    float a0 = 0.f, a1 = 0.f, a2 = 0.f, a3 = 0.f;
    float a4 = 0.f, a5 = 0.f, a6 = 0.f, a7 = 0.f;
    int j = 0;
    for (; j + 7 < n; j += 8) {          // four pairs (8 edges), MLP depth 4
      int2 e0 = se[s + j + half];
      int2 e1 = se[s + j + 2 + half];
      int2 e2 = se[s + j + 4 + half];
      int2 e3 = se[s + j + 6 + half];
      u32 f0 = *(const u32*)(s1 + (size_t)e0.x * NH + fl * 2);
      u32 f1 = *(const u32*)(s1 + (size_t)e1.x * NH + fl * 2);
      u32 f2 = *(const u32*)(s1 + (size_t)e2.x * NH + fl * 2);
      u32 f3 = *(const u32*)(s1 + (size_t)e3.x * NH + fl * 2);
      float v0 = __int_as_float(e0.y), v1 = __int_as_float(e1.y);
      float v2 = __int_as_float(e2.y), v3 = __int_as_float(e3.y);
      a0 = fmaf(v0, bf2f((u16)f0), a0);
      a1 = fmaf(v0, bf2f((u16)(f0 >> 16)), a1);
      a2 = fmaf(v1, bf2f((u16)f1), a2);
      a3 = fmaf(v1, bf2f((u16)(f1 >> 16)), a3);
      a4 = fmaf(v2, bf2f((u16)f2), a4);
      a5 = fmaf(v2, bf2f((u16)(f2 >> 16)), a5);
      a6 = fmaf(v3, bf2f((u16)f3), a6);
      a7 = fmaf(v3, bf2f((u16)(f3 >> 16)), a7);
    }
    for (; j + 3 < n; j += 4) {          // two pairs (4 edges)
      int2 e0 = se[s + j + half];
      int2 e1 = se[s + j + 2 + half];
      u32 f0 = *(const u32*)(s1 + (size_t)e0.x * NH + fl * 2);
      u32 f1 = *(const u32*)(s1 + (size_t)e1.x * NH + fl * 2);
      float v0 = __int_as_float(e0.y), v1 = __int_as_float(e1.y);
      a0 = fmaf(v0, bf2f((u16)f0), a0);
      a1 = fmaf(v0, bf2f((u16)(f0 >> 16)), a1);
      a2 = fmaf(v1, bf2f((u16)f1), a2);
      a3 = fmaf(v1, bf2f((u16)(f1 >> 16)), a3);
    }
    for (; j < n; j += 2) {              // tail (1-3 edges)
      int idx = j + half;
      bool ok = idx < n;
      int2 e = se[s + (ok ? idx : 0)];
      float v = ok ? __int_as_float(e.y) : 0.f;
      u32 f = *(const u32*)(s1 + (size_t)e.x * NH + fl * 2);
      a0 = fmaf(v, bf2f((u16)f), a0);
      a1 = fmaf(v, bf2f((u16)(f >> 16)), a1);
    }
    float t0 = (a0 + a2) + (a4 + a6);
    float t1 = (a1 + a3) + (a5 + a7);
    t0 += __shfl_xor(t0, 32, 64);        // combine even/odd halves
    t1 += __shfl_xor(t1, 32, 64);
    hpack[i] = pack2(fmaxf(t0 + bias2.x, 0.f), fmaxf(t1 + bias2.y, 0.f));
  }
  __syncthreads();   // all waves done reading se -> safe to reuse as h blocks

  u16* hl = (u16*)se + (size_t)w * 16 * HPAD;
  if (half == 0) {
#pragma unroll
    for (int i = 0; i < 16; ++i) *(u32*)&hl[i * HPAD + fl * 2] = hpack[i];
  }

  const int l15 = lane & 15, l4 = lane >> 4;
  bf16x8 afr[2];
  afr[0] = *(const bf16x8*)&hl[l15 * HPAD + l4 * 8];
  afr[1] = *(const bf16x8*)&hl[l15 * HPAD + 32 + l4 * 8];

  f32x4 acc[3];
#pragma unroll
  for (int ct = 0; ct < 3; ++ct) acc[ct] = (f32x4){0.f, 0.f, 0.f, 0.f};
#pragma unroll
  for (int ct = 0; ct < 3; ++ct) {
#pragma unroll
    for (int kk = 0; kk < 2; ++kk) {
      u16x8 bw;
#pragma unroll
      for (int j = 0; j < 8; ++j)
        bw[j] = w10s[(kk * 32 + l4 * 8 + j) * W10PAD + ct * 16 + l15];
      acc[ct] = __builtin_amdgcn_mfma_f32_16x16x32_bf16(
          afr[kk], __builtin_bit_cast(bf16x8, bw), acc[ct], 0, 0, 0);
    }
  }
#pragma unroll
  for (int ct = 0; ct < 3; ++ct) {
    int c = ct * 16 + l15;
#pragma unroll
    for (int i = 0; i < 4; ++i) {
      int grow = bkt * BROWS + w * 16 + l4 * 4 + i;
      if (c < NC && grow < NND) s2[(size_t)grow * NC + c] = f2bf(acc[ct][i]);
    }
  }
}

// ---------------- SpMM2 half-bucket: half-wave pairs, 8-edge unroll + b10 + log_softmax ----------------
__global__ __launch_bounds__(512) void spmm2h_k(const int2* __restrict__ eb2,
                                                const int* __restrict__ rowoff,
                                                const int* __restrict__ rowcnt,
                                                const u16* __restrict__ s2,
                                                const float* __restrict__ b10,
                                                float* __restrict__ out) {
  __shared__ int2 se[BCAP];
  __shared__ int roff[128];
  __shared__ int rcnt[128];
  const int bh = blockIdx.x;
  const int bkt = bh >> 1, bhalf = bh & 1;
  const int t = threadIdx.x, w = t >> 6, lane = t & 63;
  const int half = lane >> 5, fl = lane & 31;
  const bool act = fl < (NC / 2);            // fl < 20
  const int fo = act ? fl * 2 : 0;           // in-bounds class-pair offset
  const int rowBase = bkt * BROWS + bhalf * 128;
  if (t < 128) {
    roff[t] = rowoff[rowBase + t];
    rcnt[t] = rowcnt[rowBase + t];
  }
  __syncthreads();
  const int base = roff[0];
  const int nE = min(roff[127] + rcnt[127] - base, BCAP);
  for (int i = t; i < nE; i += 512) se[i] = eb2[base + i];
  __syncthreads();

  const float2 bias2 = act ? *(const float2*)(b10 + fo) : make_float2(0.f, 0.f);
#pragma unroll 1
  for (int i = 0; i < 16; ++i) {
    int r8 = w * 16 + i;                     // 8 waves x 16 rows = 128
    int s = roff[r8] - base, n = rcnt[r8];
    float a0 = 0.f, a1 = 0.f, a2 = 0.f, a3 = 0.f;
    float a4 = 0.f, a5 = 0.f, a6 = 0.f, a7 = 0.f;
    int j = 0;
    for (; j + 7 < n; j += 8) {              // four pairs (8 edges)
      int2 e0 = se[s + j + half];
      int2 e1 = se[s + j + 2 + half];
      int2 e2 = se[s + j + 4 + half];
      int2 e3 = se[s + j + 6 + half];
      u32 f0 = *(const u32*)(s2 + (size_t)e0.x * NC + fo);
      u32 f1 = *(const u32*)(s2 + (size_t)e1.x * NC + fo);
      u32 f2 = *(const u32*)(s2 + (size_t)e2.x * NC + fo);
      u32 f3 = *(const u32*)(s2 + (size_t)e3.x * NC + fo);
      float v0 = __int_as_float(e0.y), v1 = __int_as_float(e1.y);
      float v2 = __int_as_float(e2.y), v3 = __int_as_float(e3.y);
      a0 = fmaf(v0, bf2f((u16)f0), a0);
      a1 = fmaf(v0, bf2f((u16)(f0 >> 16)), a1);
      a2 = fmaf(v1, bf2f((u16)f1), a2);
      a3 = fmaf(v1, bf2f((u16)(f1 >> 16)), a3);
      a4 = fmaf(v2, bf2f((u16)f2), a4);
      a5 = fmaf(v2, bf2f((u16)(f2 >> 16)), a5);
      a6 = fmaf(v3, bf2f((u16)f3), a6);
      a7 = fmaf(v3, bf2f((u16)(f3 >> 16)), a7);
    }
    for (; j + 3 < n; j += 4) {              // two pairs (4 edges)
      int2 e0 = se[s + j + half];
      int2 e1 = se[s + j + 2 + half];
      u32 f0 = *(const u32*)(s2 + (size_t)e0.x * NC + fo);
      u32 f1 = *(const u32*)(s2 + (size_t)e1.x * NC + fo);
      float v0 = __int_as_float(e0.y), v1 = __int_as_float(e1.y);
      a0 = fmaf(v0, bf2f((u16)f0), a0);
      a1 = fmaf(v0, bf2f((u16)(f0 >> 16)), a1);
      a2 = fmaf(v1, bf2f((u16)f1), a2);
      a3 = fmaf(v1, bf2f((u16)(f1 >> 16)), a3);
    }
    for (; j < n; j += 2) {                  // tail (1-3 edges)
      int idx = j + half;
      bool ok = idx < n;
      int2 e = se[s + (ok ? idx : 0)];
      float v = ok ? __int_as_float(e.y) : 0.f;
      u32 f = *(const u32*)(s2 + (size_t)e.x * NC + fo);
      a0 = fmaf(v, bf2f((u16)f), a0);
      a1 = fmaf(v, bf2f((u16)(f >> 16)), a1);
    }
    float t0 = (a0 + a2) + (a4 + a6);
    float t1 = (a1 + a3) + (a5 + a7);
    t0 += __shfl_xor(t0, 32, 64);            // combine even/odd halves
    t1 += __shfl_xor(t1, 32, 64);
    int grow = rowBase + r8;
    if (grow >= NND) continue;
    float v0 = act ? t0 + bias2.x : -INFINITY;
    float v1 = act ? t1 + bias2.y : -INFINITY;
    float m = fmaxf(v0, v1);
#pragma unroll
    for (int o = 16; o; o >>= 1) m = fmaxf(m, __shfl_xor(m, o, 64));  // within 32-group
    float e0 = act ? __expf(v0 - m) : 0.f;
    float e1 = act ? __expf(v1 - m) : 0.f;
    float ss = e0 + e1;
#pragma unroll
    for (int o = 16; o; o >>= 1) ss += __shfl_xor(ss, o, 64);
    float l = __logf(ss);
    if (act && half == 0)
      *(float2*)(out + (size_t)grow * NC + fo) = make_float2(v0 - m - l, v1 - m - l);
  }
}

extern "C" void kernel_launch(void* const* d_in, const int* in_sizes, int n_in,
                              void* d_out, int out_size, void* d_ws, size_t ws_size,
                              hipStream_t stream) {
  const float* x    = (const float*)d_in[0];
  const float* adj  = (const float*)d_in[1];
  const float* W1   = (const float*)d_in[2];
  const float* b1   = (const float*)d_in[3];
  const float* W10  = (const float*)d_in[4];
  const float* b10  = (const float*)d_in[5];
  const int*   erow = (const int*)d_in[6];
  const int*   ecol = (const int*)d_in[7];
  float* out = (float*)d_out;

  char* p = (char*)d_ws;
  u16*  s1  = (u16*)p;    p += (size_t)NND * NH * 2;        // 12.8 MB
  u16*  s2  = (u16*)p;    p += (size_t)NND * NC * 2;        // 8 MB
  u16*  w1t = (u16*)p;    p += (size_t)NF * NH * 2;         // 64 KB
  int2* eb1 = (int2*)p;   p += (size_t)NB * BCAP * 8;       // 15.2 MB
  int2* eb2 = (int2*)p;   p += (size_t)NB * BCAP * 8;       // 15.2 MB
  int* rowoff = (int*)p;  p += (size_t)NB * BROWS * 4;      // 400 KB
  int* rowcnt = (int*)p;  p += (size_t)NB * BROWS * 4;      // 400 KB
  int* gcursor = (int*)p;

  w1t_k<<<(NF * NH + 255) / 256, 256, 0, stream>>>(W1, w1t, gcursor);
  bscatter_k<<<NEB, 1024, 0, stream>>>(adj, erow, ecol, gcursor, eb1);

  gemm1_k<<<(NND + 127) / 128, 256, 0, stream>>>(x, w1t, s1);
  spmm1f_k<<<NB, 1024, 0, stream>>>(gcursor, eb1, s1, b1, W10, s2, eb2, rowoff, rowcnt);
  spmm2h_k<<<NB * 2, 512, 0, stream>>>(eb2, rowoff, rowcnt, s2, b10, out);
}